// Round 4
// baseline (10787.879 us; speedup 1.0000x reference)
//
#include <hip/hip_runtime.h>
#include <hip/hip_bf16.h>

using bf16 = __hip_bfloat16;

#define LQ      1024
#define NBAT    2
#define DMOD    1024
#define NHEAD   16
#define DHEAD   64
#define DFFN    4096
#define MEMLEN  1024
#define TKEY    2048
#define HDIM    1024
#define SCALE_F 0.125f
#define EPS_F   1e-5f

__device__ __forceinline__ float ldf(const float* p) { return *p; }
__device__ __forceinline__ float ldf(const bf16* p) { return __bfloat162float(*p); }
__device__ __forceinline__ void stf(float* p, float v) { *p = v; }
__device__ __forceinline__ void stf(bf16* p, float v) { *p = __float2bfloat16(v); }

// ---------------- tiled GEMM: C = act(gather(A) @ B + bias), fp32 accum ----------------
// A row-major [M,K] (rows < rowsplit from A0, rest from A1). B fp32 [K,N] (external weights).
template<typename TA, typename TOUT, bool RELU>
__global__ __launch_bounds__(256)
void gemm_k(const TA* __restrict__ A0, const TA* __restrict__ A1, int rowsplit,
            const float* __restrict__ Bw, const float* __restrict__ bias,
            TOUT* __restrict__ C, int M, int N, int K)
{
    __shared__ float As[64][17];   // [row][k] padded
    __shared__ float Bs[16][64];   // [k][col]
    const int tid = threadIdx.x;
    const int tx = tid & 15;
    const int ty = tid >> 4;
    const int m0 = blockIdx.y * 64;
    const int n0 = blockIdx.x * 64;
    float acc[4][4] = {};
    for (int k0 = 0; k0 < K; k0 += 16) {
        #pragma unroll
        for (int t = 0; t < 4; t++) {
            const int idx = tid + t * 256;            // 0..1023
            const int arow = idx >> 4, ak = idx & 15;
            const int grow = m0 + arow;
            const TA* Ar = (grow < rowsplit) ? (A0 + (size_t)grow * K)
                                             : (A1 + (size_t)(grow - rowsplit) * K);
            As[arow][ak] = ldf(Ar + k0 + ak);
            const int brow = idx >> 6, bcol = idx & 63;
            Bs[brow][bcol] = ldf(Bw + (size_t)(k0 + brow) * N + n0 + bcol);
        }
        __syncthreads();
        #pragma unroll
        for (int kk = 0; kk < 16; kk++) {
            float av[4], bv[4];
            #pragma unroll
            for (int i = 0; i < 4; i++) av[i] = As[ty * 4 + i][kk];
            #pragma unroll
            for (int j = 0; j < 4; j++) bv[j] = Bs[kk][tx * 4 + j];
            #pragma unroll
            for (int i = 0; i < 4; i++)
                #pragma unroll
                for (int j = 0; j < 4; j++)
                    acc[i][j] = fmaf(av[i], bv[j], acc[i][j]);
        }
        __syncthreads();
    }
    #pragma unroll
    for (int i = 0; i < 4; i++) {
        const int m = m0 + ty * 4 + i;
        #pragma unroll
        for (int j = 0; j < 4; j++) {
            const int n = n0 + tx * 4 + j;
            float v = acc[i][j];
            if (bias) v += bias[n];
            if (RELU) v = fmaxf(v, 0.f);
            stf(C + (size_t)m * N + n, v);
        }
    }
}

// score: SCALE*((q+u)·k_j + (q+v)·r_{j+shift}); qu/qv in LDS, k/r bf16 internal
__device__ __forceinline__ float score_j(const bf16* __restrict__ kp,
                                         const bf16* __restrict__ rp,
                                         const float* qu, const float* qv)
{
    float s = 0.f;
    #pragma unroll
    for (int d = 0; d < DHEAD; d++)
        s = fmaf(qu[d], __bfloat162float(kp[d]),
            fmaf(qv[d], __bfloat162float(rp[d]), s));
    return s * SCALE_F;
}

__device__ __forceinline__ void load_qubias(const float* __restrict__ q,
                                            const float* __restrict__ ub,
                                            const float* __restrict__ vb,
                                            int i, int b, int h, int tid,
                                            float* qu, float* qv)
{
    if (tid < DHEAD) {
        float qq = q[((size_t)i * NBAT + b) * HDIM + h * DHEAD + tid];
        qu[tid] = qq + ub[h * DHEAD + tid];
        qv[tid] = qq + vb[h * DHEAD + tid];
    }
}

// ---------------- pass 1: softmax stats (m,l) per (i,b,h) ----------------
__global__ __launch_bounds__(256)
void attn_stats_k(const float* __restrict__ q, const bf16* __restrict__ kv,
                  const bf16* __restrict__ r, const float* __restrict__ ub,
                  const float* __restrict__ vb,
                  float* __restrict__ m_arr, float* __restrict__ l_arr)
{
    const int i = blockIdx.x;
    const int bh = blockIdx.y;
    const int b = bh >> 4, h = bh & 15;
    const int tid = threadIdx.x;
    __shared__ float qu[DHEAD], qv[DHEAD];
    load_qubias(q, ub, vb, i, b, h, tid, qu, qv);
    __syncthreads();
    const int jmax = i + MEMLEN;        // inclusive; >= 1024 so every thread iterates
    const int shift = LQ - 1 - i;
    float m = -3.0e38f, l = 0.f;
    for (int j = tid; j <= jmax; j += 256) {
        const bf16* kp = kv + ((size_t)j * NBAT + b) * (2 * HDIM) + h * DHEAD;
        const bf16* rp = r + ((size_t)(j + shift) * NBAT + b) * HDIM + h * DHEAD;
        float s = score_j(kp, rp, qu, qv);
        float nm = fmaxf(m, s);
        l = l * __expf(m - nm) + __expf(s - nm);
        m = nm;
    }
    __shared__ float ms[256], ls[256];
    ms[tid] = m; ls[tid] = l;
    __syncthreads();
    for (int st = 128; st > 0; st >>= 1) {
        if (tid < st) {
            float m1 = ms[tid], m2 = ms[tid + st];
            float nm = fmaxf(m1, m2);
            ls[tid] = ls[tid] * __expf(m1 - nm) + ls[tid + st] * __expf(m2 - nm);
            ms[tid] = nm;
        }
        __syncthreads();
    }
    if (tid == 0) {
        int idx = (i * NBAT + b) * NHEAD + h;
        m_arr[idx] = ms[0];
        l_arr[idx] = ls[0];
    }
}

// ---------------- pass 2: vec = P @ V per (i,b,h) ----------------
__global__ __launch_bounds__(256)
void attn_av_k(const float* __restrict__ q, const bf16* __restrict__ kv,
               const bf16* __restrict__ r, const float* __restrict__ ub,
               const float* __restrict__ vb, const float* __restrict__ m_arr,
               const float* __restrict__ l_arr, bf16* __restrict__ vec)
{
    const int i = blockIdx.x;
    const int bh = blockIdx.y;
    const int b = bh >> 4, h = bh & 15;
    const int tid = threadIdx.x;
    __shared__ float qu[DHEAD], qv[DHEAD];
    __shared__ float pbuf[256];
    load_qubias(q, ub, vb, i, b, h, tid, qu, qv);
    __syncthreads();
    const int idx = (i * NBAT + b) * NHEAD + h;
    const float mi = m_arr[idx];
    const float inv_l = 1.f / l_arr[idx];
    const int jmax = i + MEMLEN;
    const int shift = LQ - 1 - i;
    const int d = tid & 63, part = tid >> 6;
    const bf16* vbase = kv + HDIM + h * DHEAD + d;   // + (j*NBAT+b)*2*HDIM
    float accv = 0.f;
    for (int j0 = 0; j0 <= jmax; j0 += 256) {
        const int j = j0 + tid;
        float p = 0.f;
        if (j <= jmax) {
            const bf16* kp = kv + ((size_t)j * NBAT + b) * (2 * HDIM) + h * DHEAD;
            const bf16* rp = r + ((size_t)(j + shift) * NBAT + b) * HDIM + h * DHEAD;
            p = __expf(score_j(kp, rp, qu, qv) - mi) * inv_l;
        }
        pbuf[tid] = p;
        __syncthreads();
        const int jlo = part * 64;
        // j0 <= 1792, so jg <= 2047: in-bounds (p=0 beyond jmax)
        #pragma unroll 8
        for (int jj = 0; jj < 64; jj++) {
            const int jg = j0 + jlo + jj;
            accv = fmaf(pbuf[jlo + jj],
                        __bfloat162float(vbase[((size_t)jg * NBAT + b) * (2 * HDIM)]), accv);
        }
        __syncthreads();
    }
    __shared__ float vred[256];
    vred[tid] = accv;
    __syncthreads();
    if (tid < 64)
        vec[((size_t)i * NBAT + b) * HDIM + h * DHEAD + tid] =
            __float2bfloat16(vred[tid] + vred[64 + tid] + vred[128 + tid] + vred[192 + tid]);
}

// ---------------- pass 3: attn_matrix[i,:] = mean_{b,h} P (fp32 out) ----------------
__global__ __launch_bounds__(256)
void attn_mat_k(const float* __restrict__ q, const bf16* __restrict__ kv,
                const bf16* __restrict__ r, const float* __restrict__ ub,
                const float* __restrict__ vb, const float* __restrict__ m_arr,
                const float* __restrict__ l_arr, float* __restrict__ attn)
{
    const int i = blockIdx.x;
    const int tid = threadIdx.x;
    __shared__ float rowacc[TKEY];
    __shared__ float qu[DHEAD], qv[DHEAD];
    for (int j = tid; j < TKEY; j += 256) rowacc[j] = 0.f;
    const int jmax = i + MEMLEN;
    const int shift = LQ - 1 - i;
    for (int bh = 0; bh < NBAT * NHEAD; bh++) {
        const int b = bh >> 4, h = bh & 15;
        __syncthreads();
        load_qubias(q, ub, vb, i, b, h, tid, qu, qv);
        __syncthreads();
        const int idx = (i * NBAT + b) * NHEAD + h;
        const float mi = m_arr[idx];
        const float inv_l = 1.f / l_arr[idx];
        for (int j = tid; j <= jmax; j += 256) {
            const bf16* kp = kv + ((size_t)j * NBAT + b) * (2 * HDIM) + h * DHEAD;
            const bf16* rp = r + ((size_t)(j + shift) * NBAT + b) * HDIM + h * DHEAD;
            rowacc[j] += __expf(score_j(kp, rp, qu, qv) - mi) * inv_l;   // j ≡ tid mod 256: no race
        }
    }
    __syncthreads();
    const float inv = 1.f / (NBAT * NHEAD);
    for (int j = tid; j < TKEY; j += 256)
        attn[(size_t)i * TKEY + j] = rowacc[j] * inv;
}

// ---------------- fused residual + LayerNorm ----------------
template<typename T1, typename T2, typename TOUT>
__global__ __launch_bounds__(256)
void ln_k(const T1* __restrict__ a, const T2* __restrict__ c,
          const float* __restrict__ g, const float* __restrict__ bb,
          TOUT* __restrict__ out)
{
    const int row = blockIdx.x;           // L*B rows of D
    const int tid = threadIdx.x;
    const size_t base = (size_t)row * DMOD;
    float vals[4];
    float s = 0.f, sq = 0.f;
    #pragma unroll
    for (int t = 0; t < 4; t++) {
        const int dcol = tid + t * 256;
        float v = ldf(a + base + dcol) + ldf(c + base + dcol);
        vals[t] = v; s += v; sq += v * v;
    }
    __shared__ float rs[256], rq[256];
    rs[tid] = s; rq[tid] = sq;
    __syncthreads();
    for (int st = 128; st > 0; st >>= 1) {
        if (tid < st) { rs[tid] += rs[tid + st]; rq[tid] += rq[tid + st]; }
        __syncthreads();
    }
    const float mean = rs[0] / DMOD;
    const float var = rq[0] / DMOD - mean * mean;
    const float rstd = rsqrtf(fmaxf(var, 0.f) + EPS_F);
    #pragma unroll
    for (int t = 0; t < 4; t++) {
        const int dcol = tid + t * 256;
        float v = (vals[t] - mean) * rstd * g[dcol] + bb[dcol];
        stf(out + base + dcol, v);
    }
}

__global__ void fill_zero_k(float* __restrict__ p, int n) {
    int i = blockIdx.x * 256 + threadIdx.x;
    if (i < n) p[i] = 0.f;
}

extern "C" void kernel_launch(void* const* d_in, const int* in_sizes, int n_in,
                              void* d_out, int out_size, void* d_ws, size_t ws_size,
                              hipStream_t stream)
{
    // Reference dtypes are float32 — cast accordingly.
    const float* x    = (const float*)d_in[0];
    const float* pos  = (const float*)d_in[1];
    const float* ub   = (const float*)d_in[2];
    const float* vb   = (const float*)d_in[3];
    const float* memp = (const float*)d_in[4];
    const float* Wq   = (const float*)d_in[5];
    const float* Wkv  = (const float*)d_in[6];
    const float* Wo   = (const float*)d_in[7];
    const float* Wrel = (const float*)d_in[8];
    const float* ln1g = (const float*)d_in[9];
    const float* ln1b = (const float*)d_in[10];
    const float* W1   = (const float*)d_in[11];
    const float* b1   = (const float*)d_in[12];
    const float* W2   = (const float*)d_in[13];
    const float* b2   = (const float*)d_in[14];
    const float* ln2g = (const float*)d_in[15];
    const float* ln2b = (const float*)d_in[16];
    // d_in[17] = mask: analytic (j > i + MEM), unused

    // ---- workspace layout: 28.25 MB (proven to fit in round 3), lifetime-aliased ----
    // [0,16M)   : kvb bf16 (phases A,B)  -> h1 bf16 (phase C)
    // [16M,20M) : rb bf16 lower half / aout bf16 -> f2o bf16
    // [16M,24M) : rb bf16 full (A,B); out1 bf16 at [20M,24M) (phase C)
    // [24M,28M) : vecb bf16
    // [28M,+256K): m_arr, l_arr fp32
    // q (fp32) lives in d_out's lower region (dead before final LN overwrites it)
    char* wsb = (char*)d_ws;
    const size_t MB = 1048576;
    bf16*  kvb   = (bf16*)(wsb + 0);
    bf16*  h1    = (bf16*)(wsb + 0);
    bf16*  rb    = (bf16*)(wsb + 16 * MB);
    bf16*  aout  = (bf16*)(wsb + 16 * MB);
    bf16*  f2o   = (bf16*)(wsb + 16 * MB);
    bf16*  out1  = (bf16*)(wsb + 20 * MB);
    bf16*  vecb  = (bf16*)(wsb + 24 * MB);
    float* m_arr = (float*)(wsb + 28 * MB);
    float* l_arr = (float*)(wsb + 28 * MB + 131072);
    const size_t ws_need = 28 * MB + 262144;

    float* outp  = (float*)d_out;
    float* attnp = outp + (size_t)LQ * NBAT * DMOD;    // [L,T] fp32
    float* qb    = outp;                               // q scratch: exactly L*B*HDIM floats

    const dim3 blk(256);

    if (ws_size < ws_need) {
        // signal: absmax == max|ref| (~5.5) means ws too small for this plan
        fill_zero_k<<<dim3((out_size + 255) / 256), blk, 0, stream>>>(outp, out_size);
        return;
    }

    // kv = concat(memory, x) @ Wkv -> bf16 [4096 x 2048]
    gemm_k<float, bf16, false><<<dim3(2 * HDIM / 64, TKEY * NBAT / 64), blk, 0, stream>>>(
        memp, x, MEMLEN * NBAT, Wkv, nullptr, kvb, TKEY * NBAT, 2 * HDIM, DMOD);
    // r = pos_emb @ Wrel -> bf16 [4096 x 1024]
    gemm_k<float, bf16, false><<<dim3(HDIM / 64, TKEY * NBAT / 64), blk, 0, stream>>>(
        pos, pos, TKEY * NBAT, Wrel, nullptr, rb, TKEY * NBAT, HDIM, DMOD);
    // q = x @ Wq -> fp32 [2048 x 1024] into d_out lower region
    gemm_k<float, float, false><<<dim3(HDIM / 64, LQ * NBAT / 64), blk, 0, stream>>>(
        x, x, LQ * NBAT, Wq, nullptr, qb, LQ * NBAT, HDIM, DMOD);

    attn_stats_k<<<dim3(LQ, NBAT * NHEAD), blk, 0, stream>>>(qb, kvb, rb, ub, vb, m_arr, l_arr);
    attn_av_k<<<dim3(LQ, NBAT * NHEAD), blk, 0, stream>>>(qb, kvb, rb, ub, vb, m_arr, l_arr, vecb);
    attn_mat_k<<<dim3(LQ), blk, 0, stream>>>(qb, kvb, rb, ub, vb, m_arr, l_arr, attnp);

    // attn_out = vec @ Wo -> aout (kvb/rb dead from here)
    gemm_k<bf16, bf16, false><<<dim3(DMOD / 64, LQ * NBAT / 64), blk, 0, stream>>>(
        vecb, vecb, LQ * NBAT, Wo, nullptr, aout, LQ * NBAT, DMOD, HDIM);
    // out1 = LN(x + attn_out)
    ln_k<float, bf16, bf16><<<dim3(LQ * NBAT), blk, 0, stream>>>(x, aout, ln1g, ln1b, out1);
    // h1 = relu(out1 @ W1 + b1)
    gemm_k<bf16, bf16, true><<<dim3(DFFN / 64, LQ * NBAT / 64), blk, 0, stream>>>(
        out1, out1, LQ * NBAT, W1, b1, h1, LQ * NBAT, DFFN, DMOD);
    // ff = h1 @ W2 + b2 -> f2o (aout dead)
    gemm_k<bf16, bf16, false><<<dim3(DMOD / 64, LQ * NBAT / 64), blk, 0, stream>>>(
        h1, h1, LQ * NBAT, W2, b2, f2o, LQ * NBAT, DMOD, DFFN);
    // out = LN(out1 + ff) -> d_out fp32 (q scratch dead)
    ln_k<bf16, bf16, float><<<dim3(LQ * NBAT), blk, 0, stream>>>(out1, f2o, ln2g, ln2b, outp);
}

// Round 5
// 9458.086 us; speedup vs baseline: 1.1406x; 1.1406x over previous
//
#include <hip/hip_runtime.h>
#include <hip/hip_bf16.h>

using bf16 = __hip_bfloat16;

#define LQ      1024
#define NBAT    2
#define DMOD    1024
#define NHEAD   16
#define DHEAD   64
#define DFFN    4096
#define MEMLEN  1024
#define TKEY    2048
#define HDIM    1024
#define SCALE_F 0.125f
#define EPS_F   1e-5f

typedef __attribute__((ext_vector_type(8))) short short8;
typedef __attribute__((ext_vector_type(4))) float f32x4;

__device__ __forceinline__ float ldf(const float* p) { return *p; }
__device__ __forceinline__ float ldf(const bf16* p) { return __bfloat162float(*p); }
__device__ __forceinline__ void stf(float* p, float v) { *p = v; }
__device__ __forceinline__ void stf(bf16* p, float v) { *p = __float2bfloat16(v); }

// copy 4 elements (converting to bf16) into LDS, 8B store
__device__ __forceinline__ void cpy4(bf16* dst, const float* src) {
    float4 w = *(const float4*)src;
    bf16 t[4] = {__float2bfloat16(w.x), __float2bfloat16(w.y),
                 __float2bfloat16(w.z), __float2bfloat16(w.w)};
    *(uint2*)dst = *(uint2*)t;
}
__device__ __forceinline__ void cpy4(bf16* dst, const bf16* src) {
    *(uint2*)dst = *(const uint2*)src;
}

// ---------------- MFMA GEMM: C = act(gather(A) @ W + bias) ----------------
// A row-major [M,K] (rows < rowsplit from A0, rest from A1), W fp32 [K,N], C [M,N].
// M%128==0, N%128==0, K%32==0. 256 threads = 4 waves in 2x2, each wave 64x64.
template<typename TA, typename TOUT, bool RELU>
__global__ __launch_bounds__(256)
void mgemm_k(const TA* __restrict__ A0, const TA* __restrict__ A1, int rowsplit,
             const float* __restrict__ Bw, const float* __restrict__ bias,
             TOUT* __restrict__ C, int M, int N, int K)
{
    __shared__ bf16 As[128][40];   // [m][k], pad 32->40 (80B stride, 16B-aligned rows)
    __shared__ bf16 Bs[128][40];   // [n][k] (transposed at staging)
    const int tid  = threadIdx.x;
    const int m0   = blockIdx.y * 128;
    const int n0   = blockIdx.x * 128;
    const int wave = tid >> 6, lane = tid & 63;
    const int wm   = (wave >> 1) * 64, wn = (wave & 1) * 64;
    const int frow = lane & 15;          // m (A) / n (B) within 16-tile
    const int fk   = (lane >> 4) * 8;    // k offset of this lane's 8 elements

    f32x4 acc[4][4];
    #pragma unroll
    for (int i = 0; i < 4; i++)
        #pragma unroll
        for (int j = 0; j < 4; j++)
            acc[i][j] = (f32x4)(0.f);

    const int bn = tid & 127;            // B staging: n within tile
    const int bkg = (tid >> 7) * 4;      // B staging: k group base {0,4}

    for (int k0 = 0; k0 < K; k0 += 32) {
        // ---- stage A tile [128m x 32k], k-contiguous writes ----
        #pragma unroll
        for (int rep = 0; rep < 4; rep++) {
            const int idx = tid + rep * 256;       // 0..1023 quads of 4
            const int row = idx >> 3;
            const int kq  = (idx & 7) * 4;
            const int grow = m0 + row;
            const TA* Ar = (grow < rowsplit) ? (A0 + (size_t)grow * K)
                                             : (A1 + (size_t)(grow - rowsplit) * K);
            cpy4(&As[row][kq], Ar + k0 + kq);
        }
        // ---- stage B tile transposed: Bs[n][k] <- W[k0+k][n0+n] ----
        #pragma unroll
        for (int rep = 0; rep < 4; rep++) {
            const int k4 = bkg + rep * 8;          // {0,4}+{0,8,16,24}
            float v0 = Bw[(size_t)(k0 + k4 + 0) * N + n0 + bn];
            float v1 = Bw[(size_t)(k0 + k4 + 1) * N + n0 + bn];
            float v2 = Bw[(size_t)(k0 + k4 + 2) * N + n0 + bn];
            float v3 = Bw[(size_t)(k0 + k4 + 3) * N + n0 + bn];
            bf16 t[4] = {__float2bfloat16(v0), __float2bfloat16(v1),
                         __float2bfloat16(v2), __float2bfloat16(v3)};
            *(uint2*)&Bs[bn][k4] = *(uint2*)t;
        }
        __syncthreads();
        // ---- 16 MFMAs per wave ----
        short8 afr[4], bfr[4];
        #pragma unroll
        for (int i = 0; i < 4; i++)
            afr[i] = *(const short8*)&As[wm + i * 16 + frow][fk];
        #pragma unroll
        for (int j = 0; j < 4; j++)
            bfr[j] = *(const short8*)&Bs[wn + j * 16 + frow][fk];
        #pragma unroll
        for (int i = 0; i < 4; i++)
            #pragma unroll
            for (int j = 0; j < 4; j++)
                acc[i][j] = __builtin_amdgcn_mfma_f32_16x16x32_bf16(
                                afr[i], bfr[j], acc[i][j], 0, 0, 0);
        __syncthreads();
    }

    // ---- epilogue: C/D layout col=lane&15, row=(lane>>4)*4+reg ----
    const int crow = (lane >> 4) * 4, ccol = lane & 15;
    #pragma unroll
    for (int i = 0; i < 4; i++) {
        #pragma unroll
        for (int j = 0; j < 4; j++) {
            const int n = n0 + wn + j * 16 + ccol;
            float bv = bias ? bias[n] : 0.f;
            #pragma unroll
            for (int rr = 0; rr < 4; rr++) {
                const int m = m0 + wm + i * 16 + crow + rr;
                float v = acc[i][j][rr] + bv;
                if (RELU) v = fmaxf(v, 0.f);
                stf(C + (size_t)m * N + n, v);
            }
        }
    }
}

// score: SCALE*((q+u)·k_j + (q+v)·r_{j+shift})
__device__ __forceinline__ float score_j(const bf16* __restrict__ kp,
                                         const bf16* __restrict__ rp,
                                         const float* qu, const float* qv)
{
    float s = 0.f;
    #pragma unroll
    for (int d = 0; d < DHEAD; d++)
        s = fmaf(qu[d], __bfloat162float(kp[d]),
            fmaf(qv[d], __bfloat162float(rp[d]), s));
    return s * SCALE_F;
}

__device__ __forceinline__ void load_qubias(const float* __restrict__ q,
                                            const float* __restrict__ ub,
                                            const float* __restrict__ vb,
                                            int i, int b, int h, int tid,
                                            float* qu, float* qv)
{
    if (tid < DHEAD) {
        float qq = q[((size_t)i * NBAT + b) * HDIM + h * DHEAD + tid];
        qu[tid] = qq + ub[h * DHEAD + tid];
        qv[tid] = qq + vb[h * DHEAD + tid];
    }
}

// ---------------- pass 1: softmax stats (m,l) per (i,b,h) ----------------
__global__ __launch_bounds__(256)
void attn_stats_k(const float* __restrict__ q, const bf16* __restrict__ kv,
                  const bf16* __restrict__ r, const float* __restrict__ ub,
                  const float* __restrict__ vb,
                  float* __restrict__ m_arr, float* __restrict__ l_arr)
{
    const int i = blockIdx.x;
    const int bh = blockIdx.y;
    const int b = bh >> 4, h = bh & 15;
    const int tid = threadIdx.x;
    __shared__ float qu[DHEAD], qv[DHEAD];
    load_qubias(q, ub, vb, i, b, h, tid, qu, qv);
    __syncthreads();
    const int jmax = i + MEMLEN;
    const int shift = LQ - 1 - i;
    float m = -3.0e38f, l = 0.f;
    for (int j = tid; j <= jmax; j += 256) {
        const bf16* kp = kv + ((size_t)j * NBAT + b) * (2 * HDIM) + h * DHEAD;
        const bf16* rp = r + ((size_t)(j + shift) * NBAT + b) * HDIM + h * DHEAD;
        float s = score_j(kp, rp, qu, qv);
        float nm = fmaxf(m, s);
        l = l * __expf(m - nm) + __expf(s - nm);
        m = nm;
    }
    __shared__ float ms[256], ls[256];
    ms[tid] = m; ls[tid] = l;
    __syncthreads();
    for (int st = 128; st > 0; st >>= 1) {
        if (tid < st) {
            float m1 = ms[tid], m2 = ms[tid + st];
            float nm = fmaxf(m1, m2);
            ls[tid] = ls[tid] * __expf(m1 - nm) + ls[tid + st] * __expf(m2 - nm);
            ms[tid] = nm;
        }
        __syncthreads();
    }
    if (tid == 0) {
        int idx = (i * NBAT + b) * NHEAD + h;
        m_arr[idx] = ms[0];
        l_arr[idx] = ls[0];
    }
}

// ---------------- pass 2: vec = P @ V per (i,b,h) ----------------
__global__ __launch_bounds__(256)
void attn_av_k(const float* __restrict__ q, const bf16* __restrict__ kv,
               const bf16* __restrict__ r, const float* __restrict__ ub,
               const float* __restrict__ vb, const float* __restrict__ m_arr,
               const float* __restrict__ l_arr, bf16* __restrict__ vec)
{
    const int i = blockIdx.x;
    const int bh = blockIdx.y;
    const int b = bh >> 4, h = bh & 15;
    const int tid = threadIdx.x;
    __shared__ float qu[DHEAD], qv[DHEAD];
    __shared__ float pbuf[256];
    load_qubias(q, ub, vb, i, b, h, tid, qu, qv);
    __syncthreads();
    const int idx = (i * NBAT + b) * NHEAD + h;
    const float mi = m_arr[idx];
    const float inv_l = 1.f / l_arr[idx];
    const int jmax = i + MEMLEN;
    const int shift = LQ - 1 - i;
    const int d = tid & 63, part = tid >> 6;
    const bf16* vbase = kv + HDIM + h * DHEAD + d;
    float accv = 0.f;
    for (int j0 = 0; j0 <= jmax; j0 += 256) {
        const int j = j0 + tid;
        float p = 0.f;
        if (j <= jmax) {
            const bf16* kp = kv + ((size_t)j * NBAT + b) * (2 * HDIM) + h * DHEAD;
            const bf16* rp = r + ((size_t)(j + shift) * NBAT + b) * HDIM + h * DHEAD;
            p = __expf(score_j(kp, rp, qu, qv) - mi) * inv_l;
        }
        pbuf[tid] = p;
        __syncthreads();
        const int jlo = part * 64;
        #pragma unroll 8
        for (int jj = 0; jj < 64; jj++) {
            const int jg = j0 + jlo + jj;
            accv = fmaf(pbuf[jlo + jj],
                        __bfloat162float(vbase[((size_t)jg * NBAT + b) * (2 * HDIM)]), accv);
        }
        __syncthreads();
    }
    __shared__ float vred[256];
    vred[tid] = accv;
    __syncthreads();
    if (tid < 64)
        vec[((size_t)i * NBAT + b) * HDIM + h * DHEAD + tid] =
            __float2bfloat16(vred[tid] + vred[64 + tid] + vred[128 + tid] + vred[192 + tid]);
}

// ---------------- pass 3 (parallel): attn[i,j] = mean_{b,h} P ----------------
// grid (L, T/256); each thread owns one j, loops 32 bh; all qu/qv staged in LDS.
__global__ __launch_bounds__(256)
void attn_mat2_k(const float* __restrict__ q, const bf16* __restrict__ kv,
                 const bf16* __restrict__ r, const float* __restrict__ ub,
                 const float* __restrict__ vb, const float* __restrict__ m_arr,
                 const float* __restrict__ l_arr, float* __restrict__ attn)
{
    const int i = blockIdx.x;
    const int jc = blockIdx.y;
    const int tid = threadIdx.x;
    const int j = jc * 256 + tid;
    const int jmax = i + MEMLEN;
    float* orow = attn + (size_t)i * TKEY;
    if (jc * 256 > jmax) {              // fully masked chunk
        orow[j] = 0.f;
        return;
    }
    __shared__ float qu[NBAT * HDIM], qv[NBAT * HDIM];   // [b][h*64+d]
    for (int e = tid; e < NBAT * HDIM; e += 256) {
        const int b = e >> 10, rest = e & (HDIM - 1);
        float qq = q[((size_t)i * NBAT + b) * HDIM + rest];
        qu[e] = qq + ub[rest];
        qv[e] = qq + vb[rest];
    }
    __syncthreads();
    float sum = 0.f;
    if (j <= jmax) {
        const int shift = LQ - 1 - i;
        #pragma unroll 1
        for (int bh = 0; bh < NBAT * NHEAD; bh++) {
            const int b = bh >> 4, h = bh & 15;
            const bf16* kp = kv + ((size_t)j * NBAT + b) * (2 * HDIM) + h * DHEAD;
            const bf16* rp = r + ((size_t)(j + shift) * NBAT + b) * HDIM + h * DHEAD;
            const float* quh = qu + b * HDIM + h * DHEAD;
            const float* qvh = qv + b * HDIM + h * DHEAD;
            float s = score_j(kp, rp, quh, qvh);
            const int idx = (i * NBAT + b) * NHEAD + h;
            sum += __expf(s - m_arr[idx]) / l_arr[idx];
        }
    }
    orow[j] = sum * (1.f / (NBAT * NHEAD));
}

// ---------------- fused residual + LayerNorm ----------------
template<typename T1, typename T2, typename TOUT>
__global__ __launch_bounds__(256)
void ln_k(const T1* __restrict__ a, const T2* __restrict__ c,
          const float* __restrict__ g, const float* __restrict__ bb,
          TOUT* __restrict__ out)
{
    const int row = blockIdx.x;
    const int tid = threadIdx.x;
    const size_t base = (size_t)row * DMOD;
    float vals[4];
    float s = 0.f, sq = 0.f;
    #pragma unroll
    for (int t = 0; t < 4; t++) {
        const int dcol = tid + t * 256;
        float v = ldf(a + base + dcol) + ldf(c + base + dcol);
        vals[t] = v; s += v; sq += v * v;
    }
    __shared__ float rs[256], rq[256];
    rs[tid] = s; rq[tid] = sq;
    __syncthreads();
    for (int st = 128; st > 0; st >>= 1) {
        if (tid < st) { rs[tid] += rs[tid + st]; rq[tid] += rq[tid + st]; }
        __syncthreads();
    }
    const float mean = rs[0] / DMOD;
    const float var = rq[0] / DMOD - mean * mean;
    const float rstd = rsqrtf(fmaxf(var, 0.f) + EPS_F);
    #pragma unroll
    for (int t = 0; t < 4; t++) {
        const int dcol = tid + t * 256;
        float v = (vals[t] - mean) * rstd * g[dcol] + bb[dcol];
        stf(out + base + dcol, v);
    }
}

__global__ void fill_zero_k(float* __restrict__ p, int n) {
    int i = blockIdx.x * 256 + threadIdx.x;
    if (i < n) p[i] = 0.f;
}

extern "C" void kernel_launch(void* const* d_in, const int* in_sizes, int n_in,
                              void* d_out, int out_size, void* d_ws, size_t ws_size,
                              hipStream_t stream)
{
    const float* x    = (const float*)d_in[0];
    const float* pos  = (const float*)d_in[1];
    const float* ub   = (const float*)d_in[2];
    const float* vb   = (const float*)d_in[3];
    const float* memp = (const float*)d_in[4];
    const float* Wq   = (const float*)d_in[5];
    const float* Wkv  = (const float*)d_in[6];
    const float* Wo   = (const float*)d_in[7];
    const float* Wrel = (const float*)d_in[8];
    const float* ln1g = (const float*)d_in[9];
    const float* ln1b = (const float*)d_in[10];
    const float* W1   = (const float*)d_in[11];
    const float* b1   = (const float*)d_in[12];
    const float* W2   = (const float*)d_in[13];
    const float* b2   = (const float*)d_in[14];
    const float* ln2g = (const float*)d_in[15];
    const float* ln2b = (const float*)d_in[16];
    // d_in[17] = mask: analytic (j > i + MEM), unused

    // ---- workspace: 28.25 MB (proven to fit), lifetime-aliased ----
    char* wsb = (char*)d_ws;
    const size_t MB = 1048576;
    bf16*  kvb   = (bf16*)(wsb + 0);          // [T*B][2H] phases A,B
    bf16*  h1    = (bf16*)(wsb + 0);          // [L*B][DFF] phase C
    bf16*  rb    = (bf16*)(wsb + 16 * MB);    // [T*B][H]  phases A,B
    bf16*  aout  = (bf16*)(wsb + 16 * MB);    // [L*B][D]  phase B2
    bf16*  f2o   = (bf16*)(wsb + 16 * MB);    // [L*B][D]  phase C2
    bf16*  out1  = (bf16*)(wsb + 20 * MB);    // [L*B][D]
    bf16*  vecb  = (bf16*)(wsb + 24 * MB);    // [L*B][H]
    float* m_arr = (float*)(wsb + 28 * MB);
    float* l_arr = (float*)(wsb + 28 * MB + 131072);
    const size_t ws_need = 28 * MB + 262144;

    float* outp  = (float*)d_out;
    float* attnp = outp + (size_t)LQ * NBAT * DMOD;
    float* qb    = outp;                      // q scratch (dead before final LN)

    const dim3 blk(256);

    if (ws_size < ws_need) {
        fill_zero_k<<<dim3((out_size + 255) / 256), blk, 0, stream>>>(outp, out_size);
        return;
    }

    // kv = concat(memory, x) @ Wkv -> bf16 [4096 x 2048]
    mgemm_k<float, bf16, false><<<dim3(2 * HDIM / 128, TKEY * NBAT / 128), blk, 0, stream>>>(
        memp, x, MEMLEN * NBAT, Wkv, nullptr, kvb, TKEY * NBAT, 2 * HDIM, DMOD);
    // r = pos_emb @ Wrel -> bf16 [4096 x 1024]
    mgemm_k<float, bf16, false><<<dim3(HDIM / 128, TKEY * NBAT / 128), blk, 0, stream>>>(
        pos, pos, TKEY * NBAT, Wrel, nullptr, rb, TKEY * NBAT, HDIM, DMOD);
    // q = x @ Wq -> fp32 [2048 x 1024] (d_out scratch)
    mgemm_k<float, float, false><<<dim3(HDIM / 128, LQ * NBAT / 128), blk, 0, stream>>>(
        x, x, LQ * NBAT, Wq, nullptr, qb, LQ * NBAT, HDIM, DMOD);

    attn_stats_k<<<dim3(LQ, NBAT * NHEAD), blk, 0, stream>>>(qb, kvb, rb, ub, vb, m_arr, l_arr);
    attn_av_k<<<dim3(LQ, NBAT * NHEAD), blk, 0, stream>>>(qb, kvb, rb, ub, vb, m_arr, l_arr, vecb);
    attn_mat2_k<<<dim3(LQ, TKEY / 256), blk, 0, stream>>>(qb, kvb, rb, ub, vb, m_arr, l_arr, attnp);

    // attn_out = vec @ Wo -> aout (kvb/rb dead)
    mgemm_k<bf16, bf16, false><<<dim3(DMOD / 128, LQ * NBAT / 128), blk, 0, stream>>>(
        vecb, vecb, LQ * NBAT, Wo, nullptr, aout, LQ * NBAT, DMOD, HDIM);
    // out1 = LN(x + attn_out)
    ln_k<float, bf16, bf16><<<dim3(LQ * NBAT), blk, 0, stream>>>(x, aout, ln1g, ln1b, out1);
    // h1 = relu(out1 @ W1 + b1)
    mgemm_k<bf16, bf16, true><<<dim3(DFFN / 128, LQ * NBAT / 128), blk, 0, stream>>>(
        out1, out1, LQ * NBAT, W1, b1, h1, LQ * NBAT, DFFN, DMOD);
    // ff = h1 @ W2 + b2 -> f2o (aout dead)
    mgemm_k<bf16, bf16, false><<<dim3(DMOD / 128, LQ * NBAT / 128), blk, 0, stream>>>(
        h1, h1, LQ * NBAT, W2, b2, f2o, LQ * NBAT, DMOD, DFFN);
    // out = LN(out1 + ff) -> d_out fp32
    ln_k<bf16, bf16, float><<<dim3(LQ * NBAT), blk, 0, stream>>>(out1, f2o, ln2g, ln2b, outp);
}

// Round 6
// 890.968 us; speedup vs baseline: 12.1080x; 10.6155x over previous
//
#include <hip/hip_runtime.h>
#include <hip/hip_bf16.h>

using bf16 = __hip_bfloat16;

#define LQ      1024
#define NBAT    2
#define DMOD    1024
#define NHEAD   16
#define DHEAD   64
#define DFFN    4096
#define MEMLEN  1024
#define TKEY    2048
#define HDIM    1024
#define SCALE_F 0.125f
#define EPS_F   1e-5f

typedef __attribute__((ext_vector_type(8))) short short8;
typedef __attribute__((ext_vector_type(4))) float f32x4;

__device__ __forceinline__ float ldf(const float* p) { return *p; }
__device__ __forceinline__ float ldf(const bf16* p) { return __bfloat162float(*p); }
__device__ __forceinline__ void stf(float* p, float v) { *p = v; }
__device__ __forceinline__ void stf(bf16* p, float v) { *p = __float2bfloat16(v); }

// copy 4 elements (converting to bf16) into LDS, 8B store
__device__ __forceinline__ void cpy4(bf16* dst, const float* src) {
    float4 w = *(const float4*)src;
    bf16 t[4] = {__float2bfloat16(w.x), __float2bfloat16(w.y),
                 __float2bfloat16(w.z), __float2bfloat16(w.w)};
    *(uint2*)dst = *(uint2*)t;
}
__device__ __forceinline__ void cpy4(bf16* dst, const bf16* src) {
    *(uint2*)dst = *(const uint2*)src;
}

// ---------------- MFMA GEMM (unchanged from round 5, working) ----------------
template<typename TA, typename TOUT, bool RELU>
__global__ __launch_bounds__(256)
void mgemm_k(const TA* __restrict__ A0, const TA* __restrict__ A1, int rowsplit,
             const float* __restrict__ Bw, const float* __restrict__ bias,
             TOUT* __restrict__ C, int M, int N, int K)
{
    __shared__ bf16 As[128][40];
    __shared__ bf16 Bs[128][40];
    const int tid  = threadIdx.x;
    const int m0   = blockIdx.y * 128;
    const int n0   = blockIdx.x * 128;
    const int wave = tid >> 6, lane = tid & 63;
    const int wm   = (wave >> 1) * 64, wn = (wave & 1) * 64;
    const int frow = lane & 15;
    const int fk   = (lane >> 4) * 8;

    f32x4 acc[4][4];
    #pragma unroll
    for (int i = 0; i < 4; i++)
        #pragma unroll
        for (int j = 0; j < 4; j++)
            acc[i][j] = (f32x4)(0.f);

    const int bn = tid & 127;
    const int bkg = (tid >> 7) * 4;

    for (int k0 = 0; k0 < K; k0 += 32) {
        #pragma unroll
        for (int rep = 0; rep < 4; rep++) {
            const int idx = tid + rep * 256;
            const int row = idx >> 3;
            const int kq  = (idx & 7) * 4;
            const int grow = m0 + row;
            const TA* Ar = (grow < rowsplit) ? (A0 + (size_t)grow * K)
                                             : (A1 + (size_t)(grow - rowsplit) * K);
            cpy4(&As[row][kq], Ar + k0 + kq);
        }
        #pragma unroll
        for (int rep = 0; rep < 4; rep++) {
            const int k4 = bkg + rep * 8;
            float v0 = Bw[(size_t)(k0 + k4 + 0) * N + n0 + bn];
            float v1 = Bw[(size_t)(k0 + k4 + 1) * N + n0 + bn];
            float v2 = Bw[(size_t)(k0 + k4 + 2) * N + n0 + bn];
            float v3 = Bw[(size_t)(k0 + k4 + 3) * N + n0 + bn];
            bf16 t[4] = {__float2bfloat16(v0), __float2bfloat16(v1),
                         __float2bfloat16(v2), __float2bfloat16(v3)};
            *(uint2*)&Bs[bn][k4] = *(uint2*)t;
        }
        __syncthreads();
        short8 afr[4], bfr[4];
        #pragma unroll
        for (int i = 0; i < 4; i++)
            afr[i] = *(const short8*)&As[wm + i * 16 + frow][fk];
        #pragma unroll
        for (int j = 0; j < 4; j++)
            bfr[j] = *(const short8*)&Bs[wn + j * 16 + frow][fk];
        #pragma unroll
        for (int i = 0; i < 4; i++)
            #pragma unroll
            for (int j = 0; j < 4; j++)
                acc[i][j] = __builtin_amdgcn_mfma_f32_16x16x32_bf16(
                                afr[i], bfr[j], acc[i][j], 0, 0, 0);
        __syncthreads();
    }

    const int crow = (lane >> 4) * 4, ccol = lane & 15;
    #pragma unroll
    for (int i = 0; i < 4; i++) {
        #pragma unroll
        for (int j = 0; j < 4; j++) {
            const int n = n0 + wn + j * 16 + ccol;
            float bv = bias ? bias[n] : 0.f;
            #pragma unroll
            for (int rr = 0; rr < 4; rr++) {
                const int m = m0 + wm + i * 16 + crow + rr;
                float v = acc[i][j][rr] + bv;
                if (RELU) v = fmaxf(v, 0.f);
                stf(C + (size_t)m * N + n, v);
            }
        }
    }
}

// ============ fused MFMA attention: stats sweep + PV sweep ============
// grid (L/64, B*H), 256 threads = 4 waves, wave w owns rows w*16..w*16+15.
// LDS 62.4 KB: Ps aliases BDs, Vt aliases Rs (lifetime-disjoint).
__global__ __launch_bounds__(256)
void flash_attn_k(const float* __restrict__ q, const bf16* __restrict__ kv,
                  const bf16* __restrict__ rg, const float* __restrict__ ub,
                  const float* __restrict__ vb,
                  float* __restrict__ m_arr, float* __restrict__ l_arr,
                  bf16* __restrict__ vec)
{
    __shared__ bf16 Qu[64][72], Qv[64][72], Ks[64][72];
    __shared__ bf16 Rs[128][72];
    __shared__ bf16 BDs[64][128];
    bf16 (*Vt)[72] = (bf16 (*)[72])&Rs[0][0];     // V transposed [d][j]
    bf16 (*Ps)[72] = (bf16 (*)[72])&BDs[0][0];    // P tile [i][j]

    const int i0 = blockIdx.x * 64;
    const int bh = blockIdx.y;
    const int b = bh >> 4, h = bh & 15;
    const int tid = threadIdx.x;
    const int wave = tid >> 6, lane = tid & 63;
    const int g = lane >> 4, c16 = lane & 15;
    const int dib = wave * 16 + g * 4;            // this lane's row base (+reg)

    // ---- stage Qu = Q+u, Qv = Q+v (bf16) ----
    {
        const int row = tid >> 2, dbase = (tid & 3) * 16;
        const float* qrow = q + ((size_t)(i0 + row) * NBAT + b) * HDIM + h * DHEAD + dbase;
        const float* ubp = ub + h * DHEAD + dbase;
        const float* vbp = vb + h * DHEAD + dbase;
        #pragma unroll
        for (int e = 0; e < 16; e++) {
            float qq = qrow[e];
            Qu[row][dbase + e] = __float2bfloat16(qq + ubp[e]);
            Qv[row][dbase + e] = __float2bfloat16(qq + vbp[e]);
        }
    }

    float mrow[4] = {-3e38f, -3e38f, -3e38f, -3e38f};
    float lrow[4] = {0.f, 0.f, 0.f, 0.f};
    float invl[4] = {0.f, 0.f, 0.f, 0.f};
    f32x4 Oacc[4];
    #pragma unroll
    for (int nt = 0; nt < 4; nt++) Oacc[nt] = (f32x4)(0.f);

    const int ntiles = i0 / 64 + 17;              // j up to i0+63+MEM inclusive

    for (int sweep = 0; sweep < 2; sweep++) {
        for (int t = 0; t < ntiles; t++) {
            const int j0 = t * 64;
            const int jj0 = j0 + (LQ - 64) - i0;  // BD' window start (>=0 always)
            // ---- stage K tile [64j][64d] ----
            {
                const int row = tid >> 2, dbase = (tid & 3) * 16;
                const bf16* src = kv + ((size_t)(j0 + row) * NBAT + b) * (2 * HDIM)
                                     + h * DHEAD + dbase;
                *(uint4*)&Ks[row][dbase]     = *(const uint4*)src;
                *(uint4*)&Ks[row][dbase + 8] = *(const uint4*)(src + 8);
            }
            // ---- stage R window [128jj][64d], zero past T ----
            {
                const int row = tid >> 1, dbase = (tid & 1) * 32;
                const int jj = jj0 + row;
                if (jj < TKEY) {
                    const bf16* src = rg + ((size_t)jj * NBAT + b) * HDIM + h * DHEAD + dbase;
                    #pragma unroll
                    for (int u = 0; u < 4; u++)
                        *(uint4*)&Rs[row][dbase + u * 8] = *(const uint4*)(src + u * 8);
                } else {
                    const uint4 z = make_uint4(0, 0, 0, 0);
                    #pragma unroll
                    for (int u = 0; u < 4; u++)
                        *(uint4*)&Rs[row][dbase + u * 8] = z;
                }
            }
            __syncthreads();                       // staging visible
            // ---- MFMA: AC (64x64) + BD' (64x128) ----
            short8 au0 = *(const short8*)&Qu[wave * 16 + c16][g * 8];
            short8 au1 = *(const short8*)&Qu[wave * 16 + c16][32 + g * 8];
            short8 av0 = *(const short8*)&Qv[wave * 16 + c16][g * 8];
            short8 av1 = *(const short8*)&Qv[wave * 16 + c16][32 + g * 8];
            f32x4 ac[4];
            #pragma unroll
            for (int nt = 0; nt < 4; nt++) {
                ac[nt] = (f32x4)(0.f);
                ac[nt] = __builtin_amdgcn_mfma_f32_16x16x32_bf16(
                             au0, *(const short8*)&Ks[nt * 16 + c16][g * 8], ac[nt], 0, 0, 0);
                ac[nt] = __builtin_amdgcn_mfma_f32_16x16x32_bf16(
                             au1, *(const short8*)&Ks[nt * 16 + c16][32 + g * 8], ac[nt], 0, 0, 0);
            }
            #pragma unroll
            for (int nt = 0; nt < 8; nt++) {
                f32x4 bd = (f32x4)(0.f);
                bd = __builtin_amdgcn_mfma_f32_16x16x32_bf16(
                         av0, *(const short8*)&Rs[nt * 16 + c16][g * 8], bd, 0, 0, 0);
                bd = __builtin_amdgcn_mfma_f32_16x16x32_bf16(
                         av1, *(const short8*)&Rs[nt * 16 + c16][32 + g * 8], bd, 0, 0, 0);
                #pragma unroll
                for (int reg = 0; reg < 4; reg++)
                    BDs[dib + reg][nt * 16 + c16] = __float2bfloat16(bd[reg]);
            }
            __syncthreads();                       // BDs visible; Rs free
            // ---- stage V transposed (sweep 2 only; aliases Rs) ----
            if (sweep == 1) {
                const int j = tid & 63, dbase = (tid >> 6) * 16;
                const bf16* src = kv + ((size_t)(j0 + j) * NBAT + b) * (2 * HDIM)
                                     + HDIM + h * DHEAD + dbase;
                bf16 tmp[16];
                *(uint4*)&tmp[0] = *(const uint4*)src;
                *(uint4*)&tmp[8] = *(const uint4*)(src + 8);
                #pragma unroll
                for (int e = 0; e < 16; e++) Vt[dbase + e][j] = tmp[e];
            }
            // ---- combine: S = (AC + shifted BD') * scale, mask ----
            float sv[4][4];
            #pragma unroll
            for (int nt = 0; nt < 4; nt++) {
                const int dj = nt * 16 + c16;
                #pragma unroll
                for (int reg = 0; reg < 4; reg++) {
                    const int di = dib + reg;
                    float s = (ac[nt][reg] +
                               __bfloat162float(BDs[di][63 + dj - di])) * SCALE_F;
                    if (j0 + dj > i0 + di + MEMLEN) s = -1e30f;
                    sv[nt][reg] = s;
                }
            }
            if (sweep == 0) {
                // per-row (m,l) update via 16-lane butterflies
                #pragma unroll
                for (int reg = 0; reg < 4; reg++) {
                    float tm = fmaxf(fmaxf(sv[0][reg], sv[1][reg]),
                                     fmaxf(sv[2][reg], sv[3][reg]));
                    #pragma unroll
                    for (int mk = 1; mk < 16; mk <<= 1)
                        tm = fmaxf(tm, __shfl_xor(tm, mk));
                    const float nm = fmaxf(mrow[reg], tm);
                    float ps = __expf(sv[0][reg] - nm) + __expf(sv[1][reg] - nm)
                             + __expf(sv[2][reg] - nm) + __expf(sv[3][reg] - nm);
                    #pragma unroll
                    for (int mk = 1; mk < 16; mk <<= 1)
                        ps += __shfl_xor(ps, mk);
                    lrow[reg] = lrow[reg] * __expf(mrow[reg] - nm) + ps;
                    mrow[reg] = nm;
                }
                __syncthreads();                   // BDs reads done (next tile rewrites)
            } else {
                __syncthreads();                   // all BDs reads done (Ps aliases BDs)
                #pragma unroll
                for (int nt = 0; nt < 4; nt++)
                    #pragma unroll
                    for (int reg = 0; reg < 4; reg++) {
                        float p = __expf(sv[nt][reg] - mrow[reg]) * invl[reg];
                        Ps[dib + reg][nt * 16 + c16] = __float2bfloat16(p);
                    }
                __syncthreads();                   // Ps + Vt visible
                short8 p0 = *(const short8*)&Ps[wave * 16 + c16][g * 8];
                short8 p1 = *(const short8*)&Ps[wave * 16 + c16][32 + g * 8];
                #pragma unroll
                for (int nt = 0; nt < 4; nt++) {
                    Oacc[nt] = __builtin_amdgcn_mfma_f32_16x16x32_bf16(
                                   p0, *(const short8*)&Vt[nt * 16 + c16][g * 8], Oacc[nt], 0, 0, 0);
                    Oacc[nt] = __builtin_amdgcn_mfma_f32_16x16x32_bf16(
                                   p1, *(const short8*)&Vt[nt * 16 + c16][32 + g * 8], Oacc[nt], 0, 0, 0);
                }
                __syncthreads();                   // end-of-tile
            }
        }
        if (sweep == 0) {
            #pragma unroll
            for (int reg = 0; reg < 4; reg++) invl[reg] = 1.f / lrow[reg];
            if (c16 == 0) {
                #pragma unroll
                for (int reg = 0; reg < 4; reg++) {
                    const int i = i0 + dib + reg;
                    const int idx = (i * NBAT + b) * NHEAD + h;
                    m_arr[idx] = mrow[reg];
                    l_arr[idx] = lrow[reg];
                }
            }
        }
    }
    // ---- write O -> vec ----
    #pragma unroll
    for (int nt = 0; nt < 4; nt++)
        #pragma unroll
        for (int reg = 0; reg < 4; reg++)
            vec[((size_t)(i0 + dib + reg) * NBAT + b) * HDIM + h * DHEAD + nt * 16 + c16]
                = __float2bfloat16(Oacc[nt][reg]);
}

// ============ attn matrix via MFMA: grid (L/64, T/64), loop over bh ============
__global__ __launch_bounds__(256)
void attn_mat3_k(const float* __restrict__ q, const bf16* __restrict__ kv,
                 const bf16* __restrict__ rg, const float* __restrict__ ub,
                 const float* __restrict__ vb, const float* __restrict__ m_arr,
                 const float* __restrict__ l_arr, float* __restrict__ attn)
{
    const int i0 = blockIdx.x * 64;
    const int j0 = blockIdx.y * 64;
    const int tid = threadIdx.x;
    if (j0 > i0 + 63 + MEMLEN) {                   // fully masked tile
        for (int e = tid; e < 4096; e += 256)
            attn[(size_t)(i0 + (e >> 6)) * TKEY + j0 + (e & 63)] = 0.f;
        return;
    }
    __shared__ bf16 Qu[64][72], Qv[64][72], Ks[64][72];
    __shared__ bf16 Rs[128][72];
    __shared__ bf16 BDs[64][128];
    const int wave = tid >> 6, lane = tid & 63;
    const int g = lane >> 4, c16 = lane & 15;
    const int dib = wave * 16 + g * 4;
    const int jj0 = j0 + (LQ - 64) - i0;
    float psum[4][4] = {};

    for (int bh = 0; bh < NBAT * NHEAD; bh++) {
        const int b = bh >> 4, h = bh & 15;
        {
            const int row = tid >> 2, dbase = (tid & 3) * 16;
            const float* qrow = q + ((size_t)(i0 + row) * NBAT + b) * HDIM + h * DHEAD + dbase;
            const float* ubp = ub + h * DHEAD + dbase;
            const float* vbp = vb + h * DHEAD + dbase;
            #pragma unroll
            for (int e = 0; e < 16; e++) {
                float qq = qrow[e];
                Qu[row][dbase + e] = __float2bfloat16(qq + ubp[e]);
                Qv[row][dbase + e] = __float2bfloat16(qq + vbp[e]);
            }
        }
        {
            const int row = tid >> 2, dbase = (tid & 3) * 16;
            const bf16* src = kv + ((size_t)(j0 + row) * NBAT + b) * (2 * HDIM)
                                 + h * DHEAD + dbase;
            *(uint4*)&Ks[row][dbase]     = *(const uint4*)src;
            *(uint4*)&Ks[row][dbase + 8] = *(const uint4*)(src + 8);
        }
        {
            const int row = tid >> 1, dbase = (tid & 1) * 32;
            const int jj = jj0 + row;
            if (jj < TKEY) {
                const bf16* src = rg + ((size_t)jj * NBAT + b) * HDIM + h * DHEAD + dbase;
                #pragma unroll
                for (int u = 0; u < 4; u++)
                    *(uint4*)&Rs[row][dbase + u * 8] = *(const uint4*)(src + u * 8);
            } else {
                const uint4 z = make_uint4(0, 0, 0, 0);
                #pragma unroll
                for (int u = 0; u < 4; u++)
                    *(uint4*)&Rs[row][dbase + u * 8] = z;
            }
        }
        __syncthreads();
        short8 au0 = *(const short8*)&Qu[wave * 16 + c16][g * 8];
        short8 au1 = *(const short8*)&Qu[wave * 16 + c16][32 + g * 8];
        short8 av0 = *(const short8*)&Qv[wave * 16 + c16][g * 8];
        short8 av1 = *(const short8*)&Qv[wave * 16 + c16][32 + g * 8];
        f32x4 ac[4];
        #pragma unroll
        for (int nt = 0; nt < 4; nt++) {
            ac[nt] = (f32x4)(0.f);
            ac[nt] = __builtin_amdgcn_mfma_f32_16x16x32_bf16(
                         au0, *(const short8*)&Ks[nt * 16 + c16][g * 8], ac[nt], 0, 0, 0);
            ac[nt] = __builtin_amdgcn_mfma_f32_16x16x32_bf16(
                         au1, *(const short8*)&Ks[nt * 16 + c16][32 + g * 8], ac[nt], 0, 0, 0);
        }
        #pragma unroll
        for (int nt = 0; nt < 8; nt++) {
            f32x4 bd = (f32x4)(0.f);
            bd = __builtin_amdgcn_mfma_f32_16x16x32_bf16(
                     av0, *(const short8*)&Rs[nt * 16 + c16][g * 8], bd, 0, 0, 0);
            bd = __builtin_amdgcn_mfma_f32_16x16x32_bf16(
                     av1, *(const short8*)&Rs[nt * 16 + c16][32 + g * 8], bd, 0, 0, 0);
            #pragma unroll
            for (int reg = 0; reg < 4; reg++)
                BDs[dib + reg][nt * 16 + c16] = __float2bfloat16(bd[reg]);
        }
        __syncthreads();
        #pragma unroll
        for (int reg = 0; reg < 4; reg++) {
            const int di = dib + reg;
            const int idx = ((i0 + di) * NBAT + b) * NHEAD + h;
            const float mi = m_arr[idx];
            const float il = 1.f / l_arr[idx];
            #pragma unroll
            for (int nt = 0; nt < 4; nt++) {
                const int dj = nt * 16 + c16;
                float s = (ac[nt][reg] +
                           __bfloat162float(BDs[di][63 + dj - di])) * SCALE_F;
                float p = (j0 + dj > i0 + di + MEMLEN) ? 0.f : __expf(s - mi) * il;
                psum[nt][reg] += p;
            }
        }
        __syncthreads();                           // BDs reads done before restage
    }
    const float inv = 1.f / (NBAT * NHEAD);
    #pragma unroll
    for (int nt = 0; nt < 4; nt++)
        #pragma unroll
        for (int reg = 0; reg < 4; reg++)
            attn[(size_t)(i0 + dib + reg) * TKEY + j0 + nt * 16 + c16]
                = psum[nt][reg] * inv;
}

// ---------------- fused residual + LayerNorm ----------------
template<typename T1, typename T2, typename TOUT>
__global__ __launch_bounds__(256)
void ln_k(const T1* __restrict__ a, const T2* __restrict__ c,
          const float* __restrict__ g, const float* __restrict__ bb,
          TOUT* __restrict__ out)
{
    const int row = blockIdx.x;
    const int tid = threadIdx.x;
    const size_t base = (size_t)row * DMOD;
    float vals[4];
    float s = 0.f, sq = 0.f;
    #pragma unroll
    for (int t = 0; t < 4; t++) {
        const int dcol = tid + t * 256;
        float v = ldf(a + base + dcol) + ldf(c + base + dcol);
        vals[t] = v; s += v; sq += v * v;
    }
    __shared__ float rs[256], rq[256];
    rs[tid] = s; rq[tid] = sq;
    __syncthreads();
    for (int st = 128; st > 0; st >>= 1) {
        if (tid < st) { rs[tid] += rs[tid + st]; rq[tid] += rq[tid + st]; }
        __syncthreads();
    }
    const float mean = rs[0] / DMOD;
    const float var = rq[0] / DMOD - mean * mean;
    const float rstd = rsqrtf(fmaxf(var, 0.f) + EPS_F);
    #pragma unroll
    for (int t = 0; t < 4; t++) {
        const int dcol = tid + t * 256;
        float v = (vals[t] - mean) * rstd * g[dcol] + bb[dcol];
        stf(out + base + dcol, v);
    }
}

__global__ void fill_zero_k(float* __restrict__ p, int n) {
    int i = blockIdx.x * 256 + threadIdx.x;
    if (i < n) p[i] = 0.f;
}

extern "C" void kernel_launch(void* const* d_in, const int* in_sizes, int n_in,
                              void* d_out, int out_size, void* d_ws, size_t ws_size,
                              hipStream_t stream)
{
    const float* x    = (const float*)d_in[0];
    const float* pos  = (const float*)d_in[1];
    const float* ub   = (const float*)d_in[2];
    const float* vb   = (const float*)d_in[3];
    const float* memp = (const float*)d_in[4];
    const float* Wq   = (const float*)d_in[5];
    const float* Wkv  = (const float*)d_in[6];
    const float* Wo   = (const float*)d_in[7];
    const float* Wrel = (const float*)d_in[8];
    const float* ln1g = (const float*)d_in[9];
    const float* ln1b = (const float*)d_in[10];
    const float* W1   = (const float*)d_in[11];
    const float* b1   = (const float*)d_in[12];
    const float* W2   = (const float*)d_in[13];
    const float* b2   = (const float*)d_in[14];
    const float* ln2g = (const float*)d_in[15];
    const float* ln2b = (const float*)d_in[16];
    // d_in[17] = mask: analytic (j > i + MEM), unused

    // ---- workspace: 28.25 MB, lifetime-aliased ----
    char* wsb = (char*)d_ws;
    const size_t MB = 1048576;
    bf16*  kvb   = (bf16*)(wsb + 0);          // [T*B][2H] attention phases
    bf16*  h1    = (bf16*)(wsb + 0);          // [L*B][DFF] FF phase
    bf16*  rb    = (bf16*)(wsb + 16 * MB);    // [T*B][H]  attention phases
    bf16*  aout  = (bf16*)(wsb + 16 * MB);    // [L*B][D]
    bf16*  f2o   = (bf16*)(wsb + 16 * MB);    // [L*B][D]
    bf16*  out1  = (bf16*)(wsb + 20 * MB);    // [L*B][D]
    bf16*  vecb  = (bf16*)(wsb + 24 * MB);    // [L*B][H]
    float* m_arr = (float*)(wsb + 28 * MB);
    float* l_arr = (float*)(wsb + 28 * MB + 131072);
    const size_t ws_need = 28 * MB + 262144;

    float* outp  = (float*)d_out;
    float* attnp = outp + (size_t)LQ * NBAT * DMOD;
    float* qb    = outp;                      // q scratch (dead before final LN)

    const dim3 blk(256);

    if (ws_size < ws_need) {
        fill_zero_k<<<dim3((out_size + 255) / 256), blk, 0, stream>>>(outp, out_size);
        return;
    }

    // kv = concat(memory, x) @ Wkv -> bf16 [4096 x 2048]
    mgemm_k<float, bf16, false><<<dim3(2 * HDIM / 128, TKEY * NBAT / 128), blk, 0, stream>>>(
        memp, x, MEMLEN * NBAT, Wkv, nullptr, kvb, TKEY * NBAT, 2 * HDIM, DMOD);
    // r = pos_emb @ Wrel -> bf16 [4096 x 1024]
    mgemm_k<float, bf16, false><<<dim3(HDIM / 128, TKEY * NBAT / 128), blk, 0, stream>>>(
        pos, pos, TKEY * NBAT, Wrel, nullptr, rb, TKEY * NBAT, HDIM, DMOD);
    // q = x @ Wq -> fp32 [2048 x 1024] (d_out scratch)
    mgemm_k<float, float, false><<<dim3(HDIM / 128, LQ * NBAT / 128), blk, 0, stream>>>(
        x, x, LQ * NBAT, Wq, nullptr, qb, LQ * NBAT, HDIM, DMOD);

    // fused attention: stats + PV (writes m,l,vec)
    flash_attn_k<<<dim3(LQ / 64, NBAT * NHEAD), blk, 0, stream>>>(
        qb, kvb, rb, ub, vb, m_arr, l_arr, vecb);
    // attn matrix
    attn_mat3_k<<<dim3(LQ / 64, TKEY / 64), blk, 0, stream>>>(
        qb, kvb, rb, ub, vb, m_arr, l_arr, attnp);

    // attn_out = vec @ Wo -> aout (kvb/rb dead)
    mgemm_k<bf16, bf16, false><<<dim3(DMOD / 128, LQ * NBAT / 128), blk, 0, stream>>>(
        vecb, vecb, LQ * NBAT, Wo, nullptr, aout, LQ * NBAT, DMOD, HDIM);
    // out1 = LN(x + attn_out)
    ln_k<float, bf16, bf16><<<dim3(LQ * NBAT), blk, 0, stream>>>(x, aout, ln1g, ln1b, out1);
    // h1 = relu(out1 @ W1 + b1)
    mgemm_k<bf16, bf16, true><<<dim3(DFFN / 128, LQ * NBAT / 128), blk, 0, stream>>>(
        out1, out1, LQ * NBAT, W1, b1, h1, LQ * NBAT, DFFN, DMOD);
    // ff = h1 @ W2 + b2 -> f2o
    mgemm_k<bf16, bf16, false><<<dim3(DMOD / 128, LQ * NBAT / 128), blk, 0, stream>>>(
        h1, h1, LQ * NBAT, W2, b2, f2o, LQ * NBAT, DMOD, DFFN);
    // out = LN(out1 + ff) -> d_out fp32
    ln_k<bf16, bf16, float><<<dim3(LQ * NBAT), blk, 0, stream>>>(out1, f2o, ln2g, ln2b, outp);
}

// Round 7
// 783.908 us; speedup vs baseline: 13.7617x; 1.1366x over previous
//
#include <hip/hip_runtime.h>
#include <hip/hip_bf16.h>

using bf16 = __hip_bfloat16;

#define LQ      1024
#define NBAT    2
#define DMOD    1024
#define NHEAD   16
#define DHEAD   64
#define DFFN    4096
#define MEMLEN  1024
#define TKEY    2048
#define HDIM    1024
#define SCALE_F 0.125f
#define EPS_F   1e-5f

typedef __attribute__((ext_vector_type(8))) short short8;
typedef __attribute__((ext_vector_type(4))) float f32x4;

__device__ __forceinline__ float ldf(const float* p) { return *p; }
__device__ __forceinline__ float ldf(const bf16* p) { return __bfloat162float(*p); }
__device__ __forceinline__ void stf(float* p, float v) { *p = v; }
__device__ __forceinline__ void stf(bf16* p, float v) { *p = __float2bfloat16(v); }

// copy 4 elements (converting to bf16) into LDS, 8B store
__device__ __forceinline__ void cpy4(bf16* dst, const float* src) {
    float4 w = *(const float4*)src;
    bf16 t[4] = {__float2bfloat16(w.x), __float2bfloat16(w.y),
                 __float2bfloat16(w.z), __float2bfloat16(w.w)};
    *(uint2*)dst = *(uint2*)t;
}
__device__ __forceinline__ void cpy4(bf16* dst, const bf16* src) {
    *(uint2*)dst = *(const uint2*)src;
}

// ---------------- MFMA GEMM (unchanged, working) ----------------
template<typename TA, typename TOUT, bool RELU>
__global__ __launch_bounds__(256)
void mgemm_k(const TA* __restrict__ A0, const TA* __restrict__ A1, int rowsplit,
             const float* __restrict__ Bw, const float* __restrict__ bias,
             TOUT* __restrict__ C, int M, int N, int K)
{
    __shared__ bf16 As[128][40];
    __shared__ bf16 Bs[128][40];
    const int tid  = threadIdx.x;
    const int m0   = blockIdx.y * 128;
    const int n0   = blockIdx.x * 128;
    const int wave = tid >> 6, lane = tid & 63;
    const int wm   = (wave >> 1) * 64, wn = (wave & 1) * 64;
    const int frow = lane & 15;
    const int fk   = (lane >> 4) * 8;

    f32x4 acc[4][4];
    #pragma unroll
    for (int i = 0; i < 4; i++)
        #pragma unroll
        for (int j = 0; j < 4; j++)
            acc[i][j] = (f32x4)(0.f);

    const int bn = tid & 127;
    const int bkg = (tid >> 7) * 4;

    for (int k0 = 0; k0 < K; k0 += 32) {
        #pragma unroll
        for (int rep = 0; rep < 4; rep++) {
            const int idx = tid + rep * 256;
            const int row = idx >> 3;
            const int kq  = (idx & 7) * 4;
            const int grow = m0 + row;
            const TA* Ar = (grow < rowsplit) ? (A0 + (size_t)grow * K)
                                             : (A1 + (size_t)(grow - rowsplit) * K);
            cpy4(&As[row][kq], Ar + k0 + kq);
        }
        #pragma unroll
        for (int rep = 0; rep < 4; rep++) {
            const int k4 = bkg + rep * 8;
            float v0 = Bw[(size_t)(k0 + k4 + 0) * N + n0 + bn];
            float v1 = Bw[(size_t)(k0 + k4 + 1) * N + n0 + bn];
            float v2 = Bw[(size_t)(k0 + k4 + 2) * N + n0 + bn];
            float v3 = Bw[(size_t)(k0 + k4 + 3) * N + n0 + bn];
            bf16 t[4] = {__float2bfloat16(v0), __float2bfloat16(v1),
                         __float2bfloat16(v2), __float2bfloat16(v3)};
            *(uint2*)&Bs[bn][k4] = *(uint2*)t;
        }
        __syncthreads();
        short8 afr[4], bfr[4];
        #pragma unroll
        for (int i = 0; i < 4; i++)
            afr[i] = *(const short8*)&As[wm + i * 16 + frow][fk];
        #pragma unroll
        for (int j = 0; j < 4; j++)
            bfr[j] = *(const short8*)&Bs[wn + j * 16 + frow][fk];
        #pragma unroll
        for (int i = 0; i < 4; i++)
            #pragma unroll
            for (int j = 0; j < 4; j++)
                acc[i][j] = __builtin_amdgcn_mfma_f32_16x16x32_bf16(
                                afr[i], bfr[j], acc[i][j], 0, 0, 0);
        __syncthreads();
    }

    const int crow = (lane >> 4) * 4, ccol = lane & 15;
    #pragma unroll
    for (int i = 0; i < 4; i++) {
        #pragma unroll
        for (int j = 0; j < 4; j++) {
            const int n = n0 + wn + j * 16 + ccol;
            float bv = bias ? bias[n] : 0.f;
            #pragma unroll
            for (int rr = 0; rr < 4; rr++) {
                const int m = m0 + wm + i * 16 + crow + rr;
                float v = acc[i][j][rr] + bv;
                if (RELU) v = fmaxf(v, 0.f);
                stf(C + (size_t)m * N + n, v);
            }
        }
    }
}

union Frag8 { bf16 h[8]; short8 v; };

// ============ single-sweep online-softmax MFMA attention ============
// grid (L/64, B*H), 256 threads = 4 waves. Q frags in registers.
// LDS 45 KB -> 3 blocks/CU. BDs padded [64][136] (68 words % 32 = 4: conflict-free).
__global__ __launch_bounds__(256)
void flash_attn_k(const float* __restrict__ q, const bf16* __restrict__ kv,
                  const bf16* __restrict__ rg, const float* __restrict__ ub,
                  const float* __restrict__ vb,
                  float* __restrict__ m_arr, float* __restrict__ l_arr,
                  bf16* __restrict__ vec)
{
    __shared__ bf16 Ks[64][72];
    __shared__ bf16 Rs[128][72];
    __shared__ bf16 BDs[64][136];
    bf16 (*Vt)[72] = (bf16 (*)[72])&Rs[0][0];     // V^T [d][j], aliases Rs

    const int i0 = blockIdx.x * 64;
    const int bh = blockIdx.y;
    const int b = bh >> 4, h = bh & 15;
    const int tid = threadIdx.x;
    const int wave = tid >> 6, lane = tid & 63;
    const int g = lane >> 4, c16 = lane & 15;
    const int dib = wave * 16 + g * 4;            // C/D row base of this lane

    // ---- Q fragments (block-invariant) in registers ----
    Frag8 fu0, fu1, fv0, fv1;
    {
        const float* qrow = q + ((size_t)(i0 + wave * 16 + c16) * NBAT + b) * HDIM + h * DHEAD;
        const float* ubp = ub + h * DHEAD;
        const float* vbp = vb + h * DHEAD;
        #pragma unroll
        for (int e = 0; e < 8; e++) {
            float q0 = qrow[g * 8 + e], q1 = qrow[32 + g * 8 + e];
            fu0.h[e] = __float2bfloat16(q0 + ubp[g * 8 + e]);
            fu1.h[e] = __float2bfloat16(q1 + ubp[32 + g * 8 + e]);
            fv0.h[e] = __float2bfloat16(q0 + vbp[g * 8 + e]);
            fv1.h[e] = __float2bfloat16(q1 + vbp[32 + g * 8 + e]);
        }
    }

    float mrow[4] = {-3e38f, -3e38f, -3e38f, -3e38f};
    float lrow[4] = {0.f, 0.f, 0.f, 0.f};
    f32x4 Oacc[4];
    #pragma unroll
    for (int nt = 0; nt < 4; nt++) Oacc[nt] = (f32x4)(0.f);

    const int ntiles = i0 / 64 + 17;              // covers j <= i0+63+MEM

    for (int t = 0; t < ntiles; t++) {
        const int j0 = t * 64;
        const int jj0 = j0 + (LQ - 64) - i0;      // BD' window start (>= 0)
        // ---- stage K tile ----
        {
            const int row = tid >> 2, dbase = (tid & 3) * 16;
            const bf16* src = kv + ((size_t)(j0 + row) * NBAT + b) * (2 * HDIM)
                                 + h * DHEAD + dbase;
            *(uint4*)&Ks[row][dbase]     = *(const uint4*)src;
            *(uint4*)&Ks[row][dbase + 8] = *(const uint4*)(src + 8);
        }
        // ---- stage R window [128][64], zero past T ----
        {
            const int row = tid >> 1, dbase = (tid & 1) * 32;
            const int jj = jj0 + row;
            if (jj < TKEY) {
                const bf16* src = rg + ((size_t)jj * NBAT + b) * HDIM + h * DHEAD + dbase;
                #pragma unroll
                for (int u = 0; u < 4; u++)
                    *(uint4*)&Rs[row][dbase + u * 8] = *(const uint4*)(src + u * 8);
            } else {
                const uint4 z = make_uint4(0, 0, 0, 0);
                #pragma unroll
                for (int u = 0; u < 4; u++)
                    *(uint4*)&Rs[row][dbase + u * 8] = z;
            }
        }
        __syncthreads();                           // B1: staging visible
        // ---- AC (64x64) ----
        f32x4 ac[4];
        #pragma unroll
        for (int nt = 0; nt < 4; nt++) {
            ac[nt] = (f32x4)(0.f);
            ac[nt] = __builtin_amdgcn_mfma_f32_16x16x32_bf16(
                         fu0.v, *(const short8*)&Ks[nt * 16 + c16][g * 8], ac[nt], 0, 0, 0);
            ac[nt] = __builtin_amdgcn_mfma_f32_16x16x32_bf16(
                         fu1.v, *(const short8*)&Ks[nt * 16 + c16][32 + g * 8], ac[nt], 0, 0, 0);
        }
        // ---- BD' (64x128) -> BDs (group-confined rows) ----
        #pragma unroll
        for (int nt = 0; nt < 8; nt++) {
            f32x4 bd = (f32x4)(0.f);
            bd = __builtin_amdgcn_mfma_f32_16x16x32_bf16(
                     fv0.v, *(const short8*)&Rs[nt * 16 + c16][g * 8], bd, 0, 0, 0);
            bd = __builtin_amdgcn_mfma_f32_16x16x32_bf16(
                     fv1.v, *(const short8*)&Rs[nt * 16 + c16][32 + g * 8], bd, 0, 0, 0);
            #pragma unroll
            for (int reg = 0; reg < 4; reg++)
                BDs[dib + reg][nt * 16 + c16] = __float2bfloat16(bd[reg]);
        }
        __syncthreads();                           // B2: Rs reads done -> Vt staging safe
        // ---- stage V^T (aliases Rs) ----
        {
            const int j = tid & 63, dbase = (tid >> 6) * 16;
            const bf16* src = kv + ((size_t)(j0 + j) * NBAT + b) * (2 * HDIM)
                                 + HDIM + h * DHEAD + dbase;
            bf16 tmp[16];
            *(uint4*)&tmp[0] = *(const uint4*)src;
            *(uint4*)&tmp[8] = *(const uint4*)(src + 8);
            #pragma unroll
            for (int e = 0; e < 16; e++) Vt[dbase + e][j] = tmp[e];
        }
        // ---- combine scores (BDs reads are group-confined: no barrier) ----
        float sv[4][4];
        #pragma unroll
        for (int reg = 0; reg < 4; reg++) {
            const int di = dib + reg;
            const int colbase = 63 - di;
            #pragma unroll
            for (int nt = 0; nt < 4; nt++) {
                const int dj = nt * 16 + c16;
                float s = (ac[nt][reg] +
                           __bfloat162float(BDs[di][colbase + dj])) * SCALE_F;
                if (j0 + dj > i0 + di + MEMLEN) s = -1e30f;
                sv[nt][reg] = s;
            }
        }
        // ---- online stats + rescale + write P (group-confined rows) ----
        #pragma unroll
        for (int reg = 0; reg < 4; reg++) {
            float tm = fmaxf(fmaxf(sv[0][reg], sv[1][reg]),
                             fmaxf(sv[2][reg], sv[3][reg]));
            #pragma unroll
            for (int mk = 1; mk < 16; mk <<= 1)
                tm = fmaxf(tm, __shfl_xor(tm, mk));
            const float nm = fmaxf(mrow[reg], tm);
            const float alpha = __expf(mrow[reg] - nm);
            float ev[4];
            #pragma unroll
            for (int nt = 0; nt < 4; nt++) ev[nt] = __expf(sv[nt][reg] - nm);
            float ps = ev[0] + ev[1] + ev[2] + ev[3];
            #pragma unroll
            for (int mk = 1; mk < 16; mk <<= 1)
                ps += __shfl_xor(ps, mk);
            lrow[reg] = lrow[reg] * alpha + ps;
            mrow[reg] = nm;
            #pragma unroll
            for (int nt = 0; nt < 4; nt++) {
                Oacc[nt][reg] *= alpha;
                BDs[dib + reg][nt * 16 + c16] = __float2bfloat16(ev[nt]);
            }
        }
        __syncthreads();                           // B3: Vt (+P) visible
        // ---- PV MFMA ----
        short8 p0 = *(const short8*)&BDs[wave * 16 + c16][g * 8];
        short8 p1 = *(const short8*)&BDs[wave * 16 + c16][32 + g * 8];
        #pragma unroll
        for (int nt = 0; nt < 4; nt++) {
            Oacc[nt] = __builtin_amdgcn_mfma_f32_16x16x32_bf16(
                           p0, *(const short8*)&Vt[nt * 16 + c16][g * 8], Oacc[nt], 0, 0, 0);
            Oacc[nt] = __builtin_amdgcn_mfma_f32_16x16x32_bf16(
                           p1, *(const short8*)&Vt[nt * 16 + c16][32 + g * 8], Oacc[nt], 0, 0, 0);
        }
        __syncthreads();                           // B4: PV reads done before restage
    }

    // ---- finalize: normalize O, write vec + (m,l) ----
    float invl[4];
    #pragma unroll
    for (int reg = 0; reg < 4; reg++) invl[reg] = 1.f / lrow[reg];
    #pragma unroll
    for (int nt = 0; nt < 4; nt++)
        #pragma unroll
        for (int reg = 0; reg < 4; reg++)
            vec[((size_t)(i0 + dib + reg) * NBAT + b) * HDIM + h * DHEAD + nt * 16 + c16]
                = __float2bfloat16(Oacc[nt][reg] * invl[reg]);
    if (c16 == 0) {
        #pragma unroll
        for (int reg = 0; reg < 4; reg++) {
            const int idx = ((i0 + dib + reg) * NBAT + b) * NHEAD + h;
            m_arr[idx] = mrow[reg];
            l_arr[idx] = lrow[reg];
        }
    }
}

// ============ attn matrix via MFMA: grid (L/64, T/64), loop over bh ============
__global__ __launch_bounds__(256)
void attn_mat3_k(const float* __restrict__ q, const bf16* __restrict__ kv,
                 const bf16* __restrict__ rg, const float* __restrict__ ub,
                 const float* __restrict__ vb, const float* __restrict__ m_arr,
                 const float* __restrict__ l_arr, float* __restrict__ attn)
{
    const int i0 = blockIdx.x * 64;
    const int j0 = blockIdx.y * 64;
    const int tid = threadIdx.x;
    if (j0 > i0 + 63 + MEMLEN) {                   // fully masked tile
        for (int e = tid; e < 4096; e += 256)
            attn[(size_t)(i0 + (e >> 6)) * TKEY + j0 + (e & 63)] = 0.f;
        return;
    }
    __shared__ bf16 Ks[64][72];
    __shared__ bf16 Rs[128][72];
    __shared__ bf16 BDs[64][136];
    const int wave = tid >> 6, lane = tid & 63;
    const int g = lane >> 4, c16 = lane & 15;
    const int dib = wave * 16 + g * 4;
    const int jj0 = j0 + (LQ - 64) - i0;
    float psum[4][4] = {};

    for (int bh = 0; bh < NBAT * NHEAD; bh++) {
        const int b = bh >> 4, h = bh & 15;
        // ---- Q frags in registers for this (b,h) ----
        Frag8 fu0, fu1, fv0, fv1;
        {
            const float* qrow = q + ((size_t)(i0 + wave * 16 + c16) * NBAT + b) * HDIM + h * DHEAD;
            const float* ubp = ub + h * DHEAD;
            const float* vbp = vb + h * DHEAD;
            #pragma unroll
            for (int e = 0; e < 8; e++) {
                float q0 = qrow[g * 8 + e], q1 = qrow[32 + g * 8 + e];
                fu0.h[e] = __float2bfloat16(q0 + ubp[g * 8 + e]);
                fu1.h[e] = __float2bfloat16(q1 + ubp[32 + g * 8 + e]);
                fv0.h[e] = __float2bfloat16(q0 + vbp[g * 8 + e]);
                fv1.h[e] = __float2bfloat16(q1 + vbp[32 + g * 8 + e]);
            }
        }
        {
            const int row = tid >> 2, dbase = (tid & 3) * 16;
            const bf16* src = kv + ((size_t)(j0 + row) * NBAT + b) * (2 * HDIM)
                                 + h * DHEAD + dbase;
            *(uint4*)&Ks[row][dbase]     = *(const uint4*)src;
            *(uint4*)&Ks[row][dbase + 8] = *(const uint4*)(src + 8);
        }
        {
            const int row = tid >> 1, dbase = (tid & 1) * 32;
            const int jj = jj0 + row;
            if (jj < TKEY) {
                const bf16* src = rg + ((size_t)jj * NBAT + b) * HDIM + h * DHEAD + dbase;
                #pragma unroll
                for (int u = 0; u < 4; u++)
                    *(uint4*)&Rs[row][dbase + u * 8] = *(const uint4*)(src + u * 8);
            } else {
                const uint4 z = make_uint4(0, 0, 0, 0);
                #pragma unroll
                for (int u = 0; u < 4; u++)
                    *(uint4*)&Rs[row][dbase + u * 8] = z;
            }
        }
        __syncthreads();                           // staging visible
        f32x4 ac[4];
        #pragma unroll
        for (int nt = 0; nt < 4; nt++) {
            ac[nt] = (f32x4)(0.f);
            ac[nt] = __builtin_amdgcn_mfma_f32_16x16x32_bf16(
                         fu0.v, *(const short8*)&Ks[nt * 16 + c16][g * 8], ac[nt], 0, 0, 0);
            ac[nt] = __builtin_amdgcn_mfma_f32_16x16x32_bf16(
                         fu1.v, *(const short8*)&Ks[nt * 16 + c16][32 + g * 8], ac[nt], 0, 0, 0);
        }
        #pragma unroll
        for (int nt = 0; nt < 8; nt++) {
            f32x4 bd = (f32x4)(0.f);
            bd = __builtin_amdgcn_mfma_f32_16x16x32_bf16(
                     fv0.v, *(const short8*)&Rs[nt * 16 + c16][g * 8], bd, 0, 0, 0);
            bd = __builtin_amdgcn_mfma_f32_16x16x32_bf16(
                     fv1.v, *(const short8*)&Rs[nt * 16 + c16][32 + g * 8], bd, 0, 0, 0);
            #pragma unroll
            for (int reg = 0; reg < 4; reg++)
                BDs[dib + reg][nt * 16 + c16] = __float2bfloat16(bd[reg]);
        }
        // BDs reads below are group-confined to the same rows written above: no barrier
        #pragma unroll
        for (int reg = 0; reg < 4; reg++) {
            const int di = dib + reg;
            const int colbase = 63 - di;
            const int idx = ((i0 + di) * NBAT + b) * NHEAD + h;
            const float mi = m_arr[idx];
            const float il = 1.f / l_arr[idx];
            #pragma unroll
            for (int nt = 0; nt < 4; nt++) {
                const int dj = nt * 16 + c16;
                float s = (ac[nt][reg] +
                           __bfloat162float(BDs[di][colbase + dj])) * SCALE_F;
                float p = (j0 + dj > i0 + di + MEMLEN) ? 0.f : __expf(s - mi) * il;
                psum[nt][reg] += p;
            }
        }
        __syncthreads();                           // Ks/Rs reads done before restage
    }
    const float inv = 1.f / (NBAT * NHEAD);
    #pragma unroll
    for (int nt = 0; nt < 4; nt++)
        #pragma unroll
        for (int reg = 0; reg < 4; reg++)
            attn[(size_t)(i0 + dib + reg) * TKEY + j0 + nt * 16 + c16]
                = psum[nt][reg] * inv;
}

// ---------------- fused residual + LayerNorm ----------------
template<typename T1, typename T2, typename TOUT>
__global__ __launch_bounds__(256)
void ln_k(const T1* __restrict__ a, const T2* __restrict__ c,
          const float* __restrict__ g, const float* __restrict__ bb,
          TOUT* __restrict__ out)
{
    const int row = blockIdx.x;
    const int tid = threadIdx.x;
    const size_t base = (size_t)row * DMOD;
    float vals[4];
    float s = 0.f, sq = 0.f;
    #pragma unroll
    for (int t = 0; t < 4; t++) {
        const int dcol = tid + t * 256;
        float v = ldf(a + base + dcol) + ldf(c + base + dcol);
        vals[t] = v; s += v; sq += v * v;
    }
    __shared__ float rs[256], rq[256];
    rs[tid] = s; rq[tid] = sq;
    __syncthreads();
    for (int st = 128; st > 0; st >>= 1) {
        if (tid < st) { rs[tid] += rs[tid + st]; rq[tid] += rq[tid + st]; }
        __syncthreads();
    }
    const float mean = rs[0] / DMOD;
    const float var = rq[0] / DMOD - mean * mean;
    const float rstd = rsqrtf(fmaxf(var, 0.f) + EPS_F);
    #pragma unroll
    for (int t = 0; t < 4; t++) {
        const int dcol = tid + t * 256;
        float v = (vals[t] - mean) * rstd * g[dcol] + bb[dcol];
        stf(out + base + dcol, v);
    }
}

__global__ void fill_zero_k(float* __restrict__ p, int n) {
    int i = blockIdx.x * 256 + threadIdx.x;
    if (i < n) p[i] = 0.f;
}

extern "C" void kernel_launch(void* const* d_in, const int* in_sizes, int n_in,
                              void* d_out, int out_size, void* d_ws, size_t ws_size,
                              hipStream_t stream)
{
    const float* x    = (const float*)d_in[0];
    const float* pos  = (const float*)d_in[1];
    const float* ub   = (const float*)d_in[2];
    const float* vb   = (const float*)d_in[3];
    const float* memp = (const float*)d_in[4];
    const float* Wq   = (const float*)d_in[5];
    const float* Wkv  = (const float*)d_in[6];
    const float* Wo   = (const float*)d_in[7];
    const float* Wrel = (const float*)d_in[8];
    const float* ln1g = (const float*)d_in[9];
    const float* ln1b = (const float*)d_in[10];
    const float* W1   = (const float*)d_in[11];
    const float* b1   = (const float*)d_in[12];
    const float* W2   = (const float*)d_in[13];
    const float* b2   = (const float*)d_in[14];
    const float* ln2g = (const float*)d_in[15];
    const float* ln2b = (const float*)d_in[16];
    // d_in[17] = mask: analytic (j > i + MEM), unused

    // ---- workspace: 28.25 MB, lifetime-aliased ----
    char* wsb = (char*)d_ws;
    const size_t MB = 1048576;
    bf16*  kvb   = (bf16*)(wsb + 0);          // [T*B][2H] attention phases
    bf16*  h1    = (bf16*)(wsb + 0);          // [L*B][DFF] FF phase
    bf16*  rb    = (bf16*)(wsb + 16 * MB);    // [T*B][H]  attention phases
    bf16*  aout  = (bf16*)(wsb + 16 * MB);    // [L*B][D]
    bf16*  f2o   = (bf16*)(wsb + 16 * MB);    // [L*B][D]
    bf16*  out1  = (bf16*)(wsb + 20 * MB);    // [L*B][D]
    bf16*  vecb  = (bf16*)(wsb + 24 * MB);    // [L*B][H]
    float* m_arr = (float*)(wsb + 28 * MB);
    float* l_arr = (float*)(wsb + 28 * MB + 131072);
    const size_t ws_need = 28 * MB + 262144;

    float* outp  = (float*)d_out;
    float* attnp = outp + (size_t)LQ * NBAT * DMOD;
    float* qb    = outp;                      // q scratch (dead before final LN)

    const dim3 blk(256);

    if (ws_size < ws_need) {
        fill_zero_k<<<dim3((out_size + 255) / 256), blk, 0, stream>>>(outp, out_size);
        return;
    }

    // kv = concat(memory, x) @ Wkv -> bf16 [4096 x 2048]
    mgemm_k<float, bf16, false><<<dim3(2 * HDIM / 128, TKEY * NBAT / 128), blk, 0, stream>>>(
        memp, x, MEMLEN * NBAT, Wkv, nullptr, kvb, TKEY * NBAT, 2 * HDIM, DMOD);
    // r = pos_emb @ Wrel -> bf16 [4096 x 1024]
    mgemm_k<float, bf16, false><<<dim3(HDIM / 128, TKEY * NBAT / 128), blk, 0, stream>>>(
        pos, pos, TKEY * NBAT, Wrel, nullptr, rb, TKEY * NBAT, HDIM, DMOD);
    // q = x @ Wq -> fp32 [2048 x 1024] (d_out scratch)
    mgemm_k<float, float, false><<<dim3(HDIM / 128, LQ * NBAT / 128), blk, 0, stream>>>(
        x, x, LQ * NBAT, Wq, nullptr, qb, LQ * NBAT, HDIM, DMOD);

    // fused single-sweep attention (writes m,l,vec)
    flash_attn_k<<<dim3(LQ / 64, NBAT * NHEAD), blk, 0, stream>>>(
        qb, kvb, rb, ub, vb, m_arr, l_arr, vecb);
    // attn matrix
    attn_mat3_k<<<dim3(LQ / 64, TKEY / 64), blk, 0, stream>>>(
        qb, kvb, rb, ub, vb, m_arr, l_arr, attnp);

    // attn_out = vec @ Wo -> aout (kvb/rb dead)
    mgemm_k<bf16, bf16, false><<<dim3(DMOD / 128, LQ * NBAT / 128), blk, 0, stream>>>(
        vecb, vecb, LQ * NBAT, Wo, nullptr, aout, LQ * NBAT, DMOD, HDIM);
    // out1 = LN(x + attn_out)
    ln_k<float, bf16, bf16><<<dim3(LQ * NBAT), blk, 0, stream>>>(x, aout, ln1g, ln1b, out1);
    // h1 = relu(out1 @ W1 + b1)
    mgemm_k<bf16, bf16, true><<<dim3(DFFN / 128, LQ * NBAT / 128), blk, 0, stream>>>(
        out1, out1, LQ * NBAT, W1, b1, h1, LQ * NBAT, DFFN, DMOD);
    // ff = h1 @ W2 + b2 -> f2o
    mgemm_k<bf16, bf16, false><<<dim3(DMOD / 128, LQ * NBAT / 128), blk, 0, stream>>>(
        h1, h1, LQ * NBAT, W2, b2, f2o, LQ * NBAT, DMOD, DFFN);
    // out = LN(out1 + ff) -> d_out fp32
    ln_k<bf16, bf16, float><<<dim3(LQ * NBAT), blk, 0, stream>>>(out1, f2o, ln2g, ln2b, outp);
}

// Round 9
// 644.104 us; speedup vs baseline: 16.7487x; 1.2171x over previous
//
#include <hip/hip_runtime.h>
#include <hip/hip_bf16.h>

using bf16 = __hip_bfloat16;

#define LQ      1024
#define NBAT    2
#define DMOD    1024
#define NHEAD   16
#define DHEAD   64
#define DFFN    4096
#define MEMLEN  1024
#define TKEY    2048
#define HDIM    1024
#define SCALE_F 0.125f
#define EPS_F   1e-5f

typedef __attribute__((ext_vector_type(8))) short short8;
typedef __attribute__((ext_vector_type(4))) float f32x4;

__device__ __forceinline__ float ldf(const float* p) { return *p; }
__device__ __forceinline__ float ldf(const bf16* p) { return __bfloat162float(*p); }
__device__ __forceinline__ void stf(float* p, float v) { *p = v; }
__device__ __forceinline__ void stf(bf16* p, float v) { *p = __float2bfloat16(v); }

// copy 4 elements (converting to bf16) into LDS, 8B store
__device__ __forceinline__ void cpy4(bf16* dst, const float* src) {
    float4 w = *(const float4*)src;
    bf16 t[4] = {__float2bfloat16(w.x), __float2bfloat16(w.y),
                 __float2bfloat16(w.z), __float2bfloat16(w.w)};
    *(uint2*)dst = *(uint2*)t;
}
__device__ __forceinline__ void cpy4(bf16* dst, const bf16* src) {
    *(uint2*)dst = *(const uint2*)src;
}

// ---------------- MFMA GEMM, 64x64 tile, BK=64 ----------------
// A row-major [M,K] (rows < rowsplit from A0, rest from A1), W fp32 [K,N], C [M,N].
// M%64==0, N%64==0, K%64==0. 256 threads = 4 waves; wave w computes rows w*16..w*16+15.
// BUGFIX vs round 8: tile now stages 64 k-columns ([64][72]) matching the two
// MFMAs per nt that consume k 0..31 and 32..63. LDS 18.4 KB => 8 blocks/CU.
template<typename TA, typename TOUT, bool RELU>
__global__ __launch_bounds__(256)
void mgemm64_k(const TA* __restrict__ A0, const TA* __restrict__ A1, int rowsplit,
               const float* __restrict__ Bw, const float* __restrict__ bias,
               TOUT* __restrict__ C, int M, int N, int K)
{
    __shared__ bf16 As[64][72];   // [m][k], 144 B row stride (16 B aligned)
    __shared__ bf16 Bs[64][72];   // [n][k] transposed at staging
    const int tid  = threadIdx.x;
    const int m0   = blockIdx.y * 64;
    const int n0   = blockIdx.x * 64;
    const int wave = tid >> 6, lane = tid & 63;
    const int g = lane >> 4, c16 = lane & 15;

    f32x4 acc[4];
    #pragma unroll
    for (int nt = 0; nt < 4; nt++) acc[nt] = (f32x4)(0.f);

    // A staging: thread t -> row = t>>2, 16 contiguous k at colbase (t&3)*16
    const int ar = tid >> 2, akc = (tid & 3) * 16;
    const int grow = m0 + ar;
    const TA* Arow = (grow < rowsplit) ? (A0 + (size_t)grow * K)
                                       : (A1 + (size_t)(grow - rowsplit) * K);
    // B staging: thread t -> n = t&63, 16 strided k at kbase (t>>6)*16
    const int bn = tid & 63, bkb = (tid >> 6) * 16;
    const float* Bcol = Bw + n0 + bn;

    for (int k0 = 0; k0 < K; k0 += 64) {
        cpy4(&As[ar][akc],      Arow + k0 + akc);
        cpy4(&As[ar][akc + 4],  Arow + k0 + akc + 4);
        cpy4(&As[ar][akc + 8],  Arow + k0 + akc + 8);
        cpy4(&As[ar][akc + 12], Arow + k0 + akc + 12);
        {
            bf16 t16[16];
            #pragma unroll
            for (int e = 0; e < 16; e++)
                t16[e] = __float2bfloat16(Bcol[(size_t)(k0 + bkb + e) * N]);
            *(uint4*)&Bs[bn][bkb]     = *(uint4*)&t16[0];
            *(uint4*)&Bs[bn][bkb + 8] = *(uint4*)&t16[8];
        }
        __syncthreads();
        const short8 a0 = *(const short8*)&As[wave * 16 + c16][g * 8];
        const short8 a1 = *(const short8*)&As[wave * 16 + c16][32 + g * 8];
        #pragma unroll
        for (int nt = 0; nt < 4; nt++) {
            acc[nt] = __builtin_amdgcn_mfma_f32_16x16x32_bf16(
                          a0, *(const short8*)&Bs[nt * 16 + c16][g * 8], acc[nt], 0, 0, 0);
            acc[nt] = __builtin_amdgcn_mfma_f32_16x16x32_bf16(
                          a1, *(const short8*)&Bs[nt * 16 + c16][32 + g * 8], acc[nt], 0, 0, 0);
        }
        __syncthreads();
    }

    // epilogue: C/D layout col=lane&15, row=(lane>>4)*4+reg
    const int crow = (lane >> 4) * 4, ccol = lane & 15;
    #pragma unroll
    for (int nt = 0; nt < 4; nt++) {
        const int n = n0 + nt * 16 + ccol;
        const float bv = bias ? bias[n] : 0.f;
        #pragma unroll
        for (int rr = 0; rr < 4; rr++) {
            const int m = m0 + wave * 16 + crow + rr;
            float v = acc[nt][rr] + bv;
            if (RELU) v = fmaxf(v, 0.f);
            stf(C + (size_t)m * N + n, v);
        }
    }
}

union Frag8 { bf16 h[8]; short8 v; };

// ============ single-sweep online-softmax MFMA attention (round 7, working) ============
__global__ __launch_bounds__(256)
void flash_attn_k(const float* __restrict__ q, const bf16* __restrict__ kv,
                  const bf16* __restrict__ rg, const float* __restrict__ ub,
                  const float* __restrict__ vb,
                  float* __restrict__ m_arr, float* __restrict__ l_arr,
                  bf16* __restrict__ vec)
{
    __shared__ bf16 Ks[64][72];
    __shared__ bf16 Rs[128][72];
    __shared__ bf16 BDs[64][136];
    bf16 (*Vt)[72] = (bf16 (*)[72])&Rs[0][0];     // V^T [d][j], aliases Rs

    const int i0 = blockIdx.x * 64;
    const int bh = blockIdx.y;
    const int b = bh >> 4, h = bh & 15;
    const int tid = threadIdx.x;
    const int wave = tid >> 6, lane = tid & 63;
    const int g = lane >> 4, c16 = lane & 15;
    const int dib = wave * 16 + g * 4;

    Frag8 fu0, fu1, fv0, fv1;
    {
        const float* qrow = q + ((size_t)(i0 + wave * 16 + c16) * NBAT + b) * HDIM + h * DHEAD;
        const float* ubp = ub + h * DHEAD;
        const float* vbp = vb + h * DHEAD;
        #pragma unroll
        for (int e = 0; e < 8; e++) {
            float q0 = qrow[g * 8 + e], q1 = qrow[32 + g * 8 + e];
            fu0.h[e] = __float2bfloat16(q0 + ubp[g * 8 + e]);
            fu1.h[e] = __float2bfloat16(q1 + ubp[32 + g * 8 + e]);
            fv0.h[e] = __float2bfloat16(q0 + vbp[g * 8 + e]);
            fv1.h[e] = __float2bfloat16(q1 + vbp[32 + g * 8 + e]);
        }
    }

    float mrow[4] = {-3e38f, -3e38f, -3e38f, -3e38f};
    float lrow[4] = {0.f, 0.f, 0.f, 0.f};
    f32x4 Oacc[4];
    #pragma unroll
    for (int nt = 0; nt < 4; nt++) Oacc[nt] = (f32x4)(0.f);

    const int ntiles = i0 / 64 + 17;

    for (int t = 0; t < ntiles; t++) {
        const int j0 = t * 64;
        const int jj0 = j0 + (LQ - 64) - i0;
        {
            const int row = tid >> 2, dbase = (tid & 3) * 16;
            const bf16* src = kv + ((size_t)(j0 + row) * NBAT + b) * (2 * HDIM)
                                 + h * DHEAD + dbase;
            *(uint4*)&Ks[row][dbase]     = *(const uint4*)src;
            *(uint4*)&Ks[row][dbase + 8] = *(const uint4*)(src + 8);
        }
        {
            const int row = tid >> 1, dbase = (tid & 1) * 32;
            const int jj = jj0 + row;
            if (jj < TKEY) {
                const bf16* src = rg + ((size_t)jj * NBAT + b) * HDIM + h * DHEAD + dbase;
                #pragma unroll
                for (int u = 0; u < 4; u++)
                    *(uint4*)&Rs[row][dbase + u * 8] = *(const uint4*)(src + u * 8);
            } else {
                const uint4 z = make_uint4(0, 0, 0, 0);
                #pragma unroll
                for (int u = 0; u < 4; u++)
                    *(uint4*)&Rs[row][dbase + u * 8] = z;
            }
        }
        __syncthreads();
        f32x4 ac[4];
        #pragma unroll
        for (int nt = 0; nt < 4; nt++) {
            ac[nt] = (f32x4)(0.f);
            ac[nt] = __builtin_amdgcn_mfma_f32_16x16x32_bf16(
                         fu0.v, *(const short8*)&Ks[nt * 16 + c16][g * 8], ac[nt], 0, 0, 0);
            ac[nt] = __builtin_amdgcn_mfma_f32_16x16x32_bf16(
                         fu1.v, *(const short8*)&Ks[nt * 16 + c16][32 + g * 8], ac[nt], 0, 0, 0);
        }
        #pragma unroll
        for (int nt = 0; nt < 8; nt++) {
            f32x4 bd = (f32x4)(0.f);
            bd = __builtin_amdgcn_mfma_f32_16x16x32_bf16(
                     fv0.v, *(const short8*)&Rs[nt * 16 + c16][g * 8], bd, 0, 0, 0);
            bd = __builtin_amdgcn_mfma_f32_16x16x32_bf16(
                     fv1.v, *(const short8*)&Rs[nt * 16 + c16][32 + g * 8], bd, 0, 0, 0);
            #pragma unroll
            for (int reg = 0; reg < 4; reg++)
                BDs[dib + reg][nt * 16 + c16] = __float2bfloat16(bd[reg]);
        }
        __syncthreads();
        {
            const int j = tid & 63, dbase = (tid >> 6) * 16;
            const bf16* src = kv + ((size_t)(j0 + j) * NBAT + b) * (2 * HDIM)
                                 + HDIM + h * DHEAD + dbase;
            bf16 tmp[16];
            *(uint4*)&tmp[0] = *(const uint4*)src;
            *(uint4*)&tmp[8] = *(const uint4*)(src + 8);
            #pragma unroll
            for (int e = 0; e < 16; e++) Vt[dbase + e][j] = tmp[e];
        }
        float sv[4][4];
        #pragma unroll
        for (int reg = 0; reg < 4; reg++) {
            const int di = dib + reg;
            const int colbase = 63 - di;
            #pragma unroll
            for (int nt = 0; nt < 4; nt++) {
                const int dj = nt * 16 + c16;
                float s = (ac[nt][reg] +
                           __bfloat162float(BDs[di][colbase + dj])) * SCALE_F;
                if (j0 + dj > i0 + di + MEMLEN) s = -1e30f;
                sv[nt][reg] = s;
            }
        }
        #pragma unroll
        for (int reg = 0; reg < 4; reg++) {
            float tm = fmaxf(fmaxf(sv[0][reg], sv[1][reg]),
                             fmaxf(sv[2][reg], sv[3][reg]));
            #pragma unroll
            for (int mk = 1; mk < 16; mk <<= 1)
                tm = fmaxf(tm, __shfl_xor(tm, mk));
            const float nm = fmaxf(mrow[reg], tm);
            const float alpha = __expf(mrow[reg] - nm);
            float ev[4];
            #pragma unroll
            for (int nt = 0; nt < 4; nt++) ev[nt] = __expf(sv[nt][reg] - nm);
            float ps = ev[0] + ev[1] + ev[2] + ev[3];
            #pragma unroll
            for (int mk = 1; mk < 16; mk <<= 1)
                ps += __shfl_xor(ps, mk);
            lrow[reg] = lrow[reg] * alpha + ps;
            mrow[reg] = nm;
            #pragma unroll
            for (int nt = 0; nt < 4; nt++) {
                Oacc[nt][reg] *= alpha;
                BDs[dib + reg][nt * 16 + c16] = __float2bfloat16(ev[nt]);
            }
        }
        __syncthreads();
        short8 p0 = *(const short8*)&BDs[wave * 16 + c16][g * 8];
        short8 p1 = *(const short8*)&BDs[wave * 16 + c16][32 + g * 8];
        #pragma unroll
        for (int nt = 0; nt < 4; nt++) {
            Oacc[nt] = __builtin_amdgcn_mfma_f32_16x16x32_bf16(
                           p0, *(const short8*)&Vt[nt * 16 + c16][g * 8], Oacc[nt], 0, 0, 0);
            Oacc[nt] = __builtin_amdgcn_mfma_f32_16x16x32_bf16(
                           p1, *(const short8*)&Vt[nt * 16 + c16][32 + g * 8], Oacc[nt], 0, 0, 0);
        }
        __syncthreads();
    }

    float invl[4];
    #pragma unroll
    for (int reg = 0; reg < 4; reg++) invl[reg] = 1.f / lrow[reg];
    #pragma unroll
    for (int nt = 0; nt < 4; nt++)
        #pragma unroll
        for (int reg = 0; reg < 4; reg++)
            vec[((size_t)(i0 + dib + reg) * NBAT + b) * HDIM + h * DHEAD + nt * 16 + c16]
                = __float2bfloat16(Oacc[nt][reg] * invl[reg]);
    if (c16 == 0) {
        #pragma unroll
        for (int reg = 0; reg < 4; reg++) {
            const int idx = ((i0 + dib + reg) * NBAT + b) * NHEAD + h;
            m_arr[idx] = mrow[reg];
            l_arr[idx] = lrow[reg];
        }
    }
}

// ============ attn matrix via MFMA (round 7, working) ============
__global__ __launch_bounds__(256)
void attn_mat3_k(const float* __restrict__ q, const bf16* __restrict__ kv,
                 const bf16* __restrict__ rg, const float* __restrict__ ub,
                 const float* __restrict__ vb, const float* __restrict__ m_arr,
                 const float* __restrict__ l_arr, float* __restrict__ attn)
{
    const int i0 = blockIdx.x * 64;
    const int j0 = blockIdx.y * 64;
    const int tid = threadIdx.x;
    if (j0 > i0 + 63 + MEMLEN) {
        for (int e = tid; e < 4096; e += 256)
            attn[(size_t)(i0 + (e >> 6)) * TKEY + j0 + (e & 63)] = 0.f;
        return;
    }
    __shared__ bf16 Ks[64][72];
    __shared__ bf16 Rs[128][72];
    __shared__ bf16 BDs[64][136];
    const int wave = tid >> 6, lane = tid & 63;
    const int g = lane >> 4, c16 = lane & 15;
    const int dib = wave * 16 + g * 4;
    const int jj0 = j0 + (LQ - 64) - i0;
    float psum[4][4] = {};

    for (int bh = 0; bh < NBAT * NHEAD; bh++) {
        const int b = bh >> 4, h = bh & 15;
        Frag8 fu0, fu1, fv0, fv1;
        {
            const float* qrow = q + ((size_t)(i0 + wave * 16 + c16) * NBAT + b) * HDIM + h * DHEAD;
            const float* ubp = ub + h * DHEAD;
            const float* vbp = vb + h * DHEAD;
            #pragma unroll
            for (int e = 0; e < 8; e++) {
                float q0 = qrow[g * 8 + e], q1 = qrow[32 + g * 8 + e];
                fu0.h[e] = __float2bfloat16(q0 + ubp[g * 8 + e]);
                fu1.h[e] = __float2bfloat16(q1 + ubp[32 + g * 8 + e]);
                fv0.h[e] = __float2bfloat16(q0 + vbp[g * 8 + e]);
                fv1.h[e] = __float2bfloat16(q1 + vbp[32 + g * 8 + e]);
            }
        }
        {
            const int row = tid >> 2, dbase = (tid & 3) * 16;
            const bf16* src = kv + ((size_t)(j0 + row) * NBAT + b) * (2 * HDIM)
                                 + h * DHEAD + dbase;
            *(uint4*)&Ks[row][dbase]     = *(const uint4*)src;
            *(uint4*)&Ks[row][dbase + 8] = *(const uint4*)(src + 8);
        }
        {
            const int row = tid >> 1, dbase = (tid & 1) * 32;
            const int jj = jj0 + row;
            if (jj < TKEY) {
                const bf16* src = rg + ((size_t)jj * NBAT + b) * HDIM + h * DHEAD + dbase;
                #pragma unroll
                for (int u = 0; u < 4; u++)
                    *(uint4*)&Rs[row][dbase + u * 8] = *(const uint4*)(src + u * 8);
            } else {
                const uint4 z = make_uint4(0, 0, 0, 0);
                #pragma unroll
                for (int u = 0; u < 4; u++)
                    *(uint4*)&Rs[row][dbase + u * 8] = z;
            }
        }
        __syncthreads();
        f32x4 ac[4];
        #pragma unroll
        for (int nt = 0; nt < 4; nt++) {
            ac[nt] = (f32x4)(0.f);
            ac[nt] = __builtin_amdgcn_mfma_f32_16x16x32_bf16(
                         fu0.v, *(const short8*)&Ks[nt * 16 + c16][g * 8], ac[nt], 0, 0, 0);
            ac[nt] = __builtin_amdgcn_mfma_f32_16x16x32_bf16(
                         fu1.v, *(const short8*)&Ks[nt * 16 + c16][32 + g * 8], ac[nt], 0, 0, 0);
        }
        #pragma unroll
        for (int nt = 0; nt < 8; nt++) {
            f32x4 bd = (f32x4)(0.f);
            bd = __builtin_amdgcn_mfma_f32_16x16x32_bf16(
                     fv0.v, *(const short8*)&Rs[nt * 16 + c16][g * 8], bd, 0, 0, 0);
            bd = __builtin_amdgcn_mfma_f32_16x16x32_bf16(
                     fv1.v, *(const short8*)&Rs[nt * 16 + c16][32 + g * 8], bd, 0, 0, 0);
            #pragma unroll
            for (int reg = 0; reg < 4; reg++)
                BDs[dib + reg][nt * 16 + c16] = __float2bfloat16(bd[reg]);
        }
        #pragma unroll
        for (int reg = 0; reg < 4; reg++) {
            const int di = dib + reg;
            const int colbase = 63 - di;
            const int idx = ((i0 + di) * NBAT + b) * NHEAD + h;
            const float mi = m_arr[idx];
            const float il = 1.f / l_arr[idx];
            #pragma unroll
            for (int nt = 0; nt < 4; nt++) {
                const int dj = nt * 16 + c16;
                float s = (ac[nt][reg] +
                           __bfloat162float(BDs[di][colbase + dj])) * SCALE_F;
                float p = (j0 + dj > i0 + di + MEMLEN) ? 0.f : __expf(s - mi) * il;
                psum[nt][reg] += p;
            }
        }
        __syncthreads();
    }
    const float inv = 1.f / (NBAT * NHEAD);
    #pragma unroll
    for (int nt = 0; nt < 4; nt++)
        #pragma unroll
        for (int reg = 0; reg < 4; reg++)
            attn[(size_t)(i0 + dib + reg) * TKEY + j0 + nt * 16 + c16]
                = psum[nt][reg] * inv;
}

// ---------------- fused residual + LayerNorm ----------------
template<typename T1, typename T2, typename TOUT>
__global__ __launch_bounds__(256)
void ln_k(const T1* __restrict__ a, const T2* __restrict__ c,
          const float* __restrict__ g, const float* __restrict__ bb,
          TOUT* __restrict__ out)
{
    const int row = blockIdx.x;
    const int tid = threadIdx.x;
    const size_t base = (size_t)row * DMOD;
    float vals[4];
    float s = 0.f, sq = 0.f;
    #pragma unroll
    for (int t = 0; t < 4; t++) {
        const int dcol = tid + t * 256;
        float v = ldf(a + base + dcol) + ldf(c + base + dcol);
        vals[t] = v; s += v; sq += v * v;
    }
    __shared__ float rs[256], rq[256];
    rs[tid] = s; rq[tid] = sq;
    __syncthreads();
    for (int st = 128; st > 0; st >>= 1) {
        if (tid < st) { rs[tid] += rs[tid + st]; rq[tid] += rq[tid + st]; }
        __syncthreads();
    }
    const float mean = rs[0] / DMOD;
    const float var = rq[0] / DMOD - mean * mean;
    const float rstd = rsqrtf(fmaxf(var, 0.f) + EPS_F);
    #pragma unroll
    for (int t = 0; t < 4; t++) {
        const int dcol = tid + t * 256;
        float v = (vals[t] - mean) * rstd * g[dcol] + bb[dcol];
        stf(out + base + dcol, v);
    }
}

__global__ void fill_zero_k(float* __restrict__ p, int n) {
    int i = blockIdx.x * 256 + threadIdx.x;
    if (i < n) p[i] = 0.f;
}

extern "C" void kernel_launch(void* const* d_in, const int* in_sizes, int n_in,
                              void* d_out, int out_size, void* d_ws, size_t ws_size,
                              hipStream_t stream)
{
    const float* x    = (const float*)d_in[0];
    const float* pos  = (const float*)d_in[1];
    const float* ub   = (const float*)d_in[2];
    const float* vb   = (const float*)d_in[3];
    const float* memp = (const float*)d_in[4];
    const float* Wq   = (const float*)d_in[5];
    const float* Wkv  = (const float*)d_in[6];
    const float* Wo   = (const float*)d_in[7];
    const float* Wrel = (const float*)d_in[8];
    const float* ln1g = (const float*)d_in[9];
    const float* ln1b = (const float*)d_in[10];
    const float* W1   = (const float*)d_in[11];
    const float* b1   = (const float*)d_in[12];
    const float* W2   = (const float*)d_in[13];
    const float* b2   = (const float*)d_in[14];
    const float* ln2g = (const float*)d_in[15];
    const float* ln2b = (const float*)d_in[16];
    // d_in[17] = mask: analytic (j > i + MEM), unused

    // ---- workspace: 28.25 MB, lifetime-aliased ----
    char* wsb = (char*)d_ws;
    const size_t MB = 1048576;
    bf16*  kvb   = (bf16*)(wsb + 0);          // [T*B][2H] attention phases
    bf16*  h1    = (bf16*)(wsb + 0);          // [L*B][DFF] FF phase
    bf16*  rb    = (bf16*)(wsb + 16 * MB);    // [T*B][H]  attention phases
    bf16*  aout  = (bf16*)(wsb + 16 * MB);    // [L*B][D]
    bf16*  f2o   = (bf16*)(wsb + 16 * MB);    // [L*B][D]
    bf16*  out1  = (bf16*)(wsb + 20 * MB);    // [L*B][D]
    bf16*  vecb  = (bf16*)(wsb + 24 * MB);    // [L*B][H]
    float* m_arr = (float*)(wsb + 28 * MB);
    float* l_arr = (float*)(wsb + 28 * MB + 131072);
    const size_t ws_need = 28 * MB + 262144;

    float* outp  = (float*)d_out;
    float* attnp = outp + (size_t)LQ * NBAT * DMOD;
    float* qb    = outp;                      // q scratch (dead before final LN)

    const dim3 blk(256);

    if (ws_size < ws_need) {
        fill_zero_k<<<dim3((out_size + 255) / 256), blk, 0, stream>>>(outp, out_size);
        return;
    }

    // kv = concat(memory, x) @ Wkv -> bf16 [4096 x 2048]  (2048 blocks)
    mgemm64_k<float, bf16, false><<<dim3(2 * HDIM / 64, TKEY * NBAT / 64), blk, 0, stream>>>(
        memp, x, MEMLEN * NBAT, Wkv, nullptr, kvb, TKEY * NBAT, 2 * HDIM, DMOD);
    // r = pos_emb @ Wrel -> bf16 [4096 x 1024]  (1024 blocks)
    mgemm64_k<float, bf16, false><<<dim3(HDIM / 64, TKEY * NBAT / 64), blk, 0, stream>>>(
        pos, pos, TKEY * NBAT, Wrel, nullptr, rb, TKEY * NBAT, HDIM, DMOD);
    // q = x @ Wq -> fp32 [2048 x 1024]  (512 blocks)
    mgemm64_k<float, float, false><<<dim3(HDIM / 64, LQ * NBAT / 64), blk, 0, stream>>>(
        x, x, LQ * NBAT, Wq, nullptr, qb, LQ * NBAT, HDIM, DMOD);

    // fused single-sweep attention (writes m,l,vec)
    flash_attn_k<<<dim3(LQ / 64, NBAT * NHEAD), blk, 0, stream>>>(
        qb, kvb, rb, ub, vb, m_arr, l_arr, vecb);
    // attn matrix
    attn_mat3_k<<<dim3(LQ / 64, TKEY / 64), blk, 0, stream>>>(
        qb, kvb, rb, ub, vb, m_arr, l_arr, attnp);

    // attn_out = vec @ Wo -> aout (kvb/rb dead)  (512 blocks)
    mgemm64_k<bf16, bf16, false><<<dim3(DMOD / 64, LQ * NBAT / 64), blk, 0, stream>>>(
        vecb, vecb, LQ * NBAT, Wo, nullptr, aout, LQ * NBAT, DMOD, HDIM);
    // out1 = LN(x + attn_out)
    ln_k<float, bf16, bf16><<<dim3(LQ * NBAT), blk, 0, stream>>>(x, aout, ln1g, ln1b, out1);
    // h1 = relu(out1 @ W1 + b1)  (2048 blocks)
    mgemm64_k<bf16, bf16, true><<<dim3(DFFN / 64, LQ * NBAT / 64), blk, 0, stream>>>(
        out1, out1, LQ * NBAT, W1, b1, h1, LQ * NBAT, DFFN, DMOD);
    // ff = h1 @ W2 + b2 -> f2o  (512 blocks)
    mgemm64_k<bf16, bf16, false><<<dim3(DMOD / 64, LQ * NBAT / 64), blk, 0, stream>>>(
        h1, h1, LQ * NBAT, W2, b2, f2o, LQ * NBAT, DMOD, DFFN);
    // out = LN(out1 + ff) -> d_out fp32
    ln_k<bf16, bf16, float><<<dim3(LQ * NBAT), blk, 0, stream>>>(out1, f2o, ln2g, ln2b, outp);
}